// Round 5
// baseline (604.050 us; speedup 1.0000x reference)
//
#include <hip/hip_runtime.h>

#define NN 50000
#define NE 800000
#define NG 512
#define HC 64
#define NL 5
#define GD_COLS 321
#define BN_EPS 1e-5f
#define DEG_CAP 64  // max degree: Poisson(16), P(>64) ~ 1e-18 — fixed-stride edge table

#define NBK 196   // destination buckets: ceil(NN/256)
#define CAPB 5120 // per-bucket edge capacity (lambda=4096, +16 sigma)
#define LCAP 64   // per-block LDS bin capacity (lambda=21, +9 sigma; global fallback)

typedef unsigned short bf16_t;
typedef unsigned int uiv4 __attribute__((ext_vector_type(4)));
typedef __attribute__((ext_vector_type(8))) short short8v;   // 8 bf16 = 4 VGPRs (MFMA A/B frag)
typedef __attribute__((ext_vector_type(4))) float f32x4;     // MFMA C/D frag
typedef __attribute__((ext_vector_type(4))) unsigned uint4v;

static __device__ __forceinline__ unsigned f2bfbits(float f) {
    unsigned u = __float_as_uint(f);
    return (u + 0x7FFFu + ((u >> 16) & 1u)) >> 16;
}
static __device__ __forceinline__ bf16_t f2bf(float f) { return (bf16_t)f2bfbits(f); }
static __device__ __forceinline__ float bf2f(bf16_t h) {
    return __uint_as_float(((unsigned)h) << 16);
}
static __device__ __forceinline__ float bflo(unsigned w) { return __uint_as_float(w << 16); }
static __device__ __forceinline__ float bfhi(unsigned w) {
    return __uint_as_float(w & 0xffff0000u);
}

// ---- shared MFMA GEMM phase: OUT[64x64] = ZW[64x64] @ WSM[64x64] + bias, + per-channel stats.
// zw: packed bf16 pairs, row-major [64 rows][33 words] (word kk = z[2kk],z[2kk+1]).
// wsm: packed bf16 pairs of W by column: wsm[c*33+kk] = (W[2kk][c], W[2kk+1][c]).
// Wave wid owns output tiles (tr=wid>>1, tc = (wid&1)*2 (+1)).
// A-frag: lane holds A[tr*16+(l&15)][kc*32+8*(l>>4)+0..7] (contiguous-k, m97/m201 layout).
// C/D: col=lane&15, row=(lane>>4)*4+j (m89-verified).
static __device__ __forceinline__ void mfma_gemm_phase(
    const unsigned* zw, const unsigned* wsm, const float* __restrict__ bias,
    bf16_t* __restrict__ out, float* __restrict__ statsOut, float (*redS)[64],
    float (*redQ)[64], int r0, int t, int lane, int wid) {
    int l15 = lane & 15, l4 = lane >> 4;
    int tr = wid >> 1;
    int tc0 = (wid & 1) * 2;
    f32x4 d0 = {0.f, 0.f, 0.f, 0.f}, d1 = {0.f, 0.f, 0.f, 0.f};
    const unsigned* arow = &zw[(tr * 16 + l15) * 33];
    const unsigned* brow0 = &wsm[(tc0 * 16 + l15) * 33];
    const unsigned* brow1 = &wsm[((tc0 + 1) * 16 + l15) * 33];
#pragma unroll
    for (int kc = 0; kc < 2; ++kc) {
        int kb = kc * 16 + l4 * 4;
        uint4v aw = {arow[kb], arow[kb + 1], arow[kb + 2], arow[kb + 3]};
        uint4v bw0 = {brow0[kb], brow0[kb + 1], brow0[kb + 2], brow0[kb + 3]};
        uint4v bw1 = {brow1[kb], brow1[kb + 1], brow1[kb + 2], brow1[kb + 3]};
        short8v af = __builtin_bit_cast(short8v, aw);
        d0 = __builtin_amdgcn_mfma_f32_16x16x32_bf16(af, __builtin_bit_cast(short8v, bw0), d0,
                                                     0, 0, 0);
        d1 = __builtin_amdgcn_mfma_f32_16x16x32_bf16(af, __builtin_bit_cast(short8v, bw1), d1,
                                                     0, 0, 0);
    }
    int c0 = tc0 * 16 + l15, c1 = c0 + 16;
    float bv0 = bias[c0], bv1 = bias[c1];
    float s0 = 0.f, q0 = 0.f, s1 = 0.f, q1 = 0.f;
#pragma unroll
    for (int j = 0; j < 4; ++j) {
        int gr = r0 + tr * 16 + l4 * 4 + j;
        if (gr < NN) {
            float v0 = d0[j] + bv0, v1 = d1[j] + bv1;
            out[(size_t)gr * HC + c0] = f2bf(v0);
            out[(size_t)gr * HC + c1] = f2bf(v1);
            s0 += v0;
            q0 += v0 * v0;
            s1 += v1;
            q1 += v1 * v1;
        }
    }
    // fold the 4 lanes (l>>4 groups) that share a column
    s0 += __shfl_xor(s0, 16); s0 += __shfl_xor(s0, 32);
    q0 += __shfl_xor(q0, 16); q0 += __shfl_xor(q0, 32);
    s1 += __shfl_xor(s1, 16); s1 += __shfl_xor(s1, 32);
    q1 += __shfl_xor(q1, 16); q1 += __shfl_xor(q1, 32);
    // wave covers channels [tc0*16, tc0*16+32); zero-fill the other 32 for the block reduce
    if (l4 == 0) { redS[wid][c0] = s0; redQ[wid][c0] = q0; }
    else if (l4 == 1) { redS[wid][c1] = s1; redQ[wid][c1] = q1; }
    else if (l4 == 2) { redS[wid][c0 ^ 32] = 0.f; redQ[wid][c0 ^ 32] = 0.f; }
    else { redS[wid][c1 ^ 32] = 0.f; redQ[wid][c1 ^ 32] = 0.f; }
    __syncthreads();
    if (t < 64) {
        float ts = 0.f, t2 = 0.f;
#pragma unroll
        for (int k = 0; k < 8; ++k) {
            ts += redS[k][t];
            t2 += redQ[k][t];
        }
        atomicAdd(&statsOut[t], ts);
        atomicAdd(&statsOut[64 + t], t2);
    }
}

// ---------------- edge-table build, pass A: LDS-binned bucket append ----------------
// Each block bins 4096 edges by coarse destination (d>>8) in LDS, then flushes each
// bin as a contiguous u32 burst into ebuf (full-line writes — no scatter amplification).
// Encoding: enc = s | (d&255)<<16 (s < 2^16, bucket id implied by ebuf region).
// Also zeroes stats + gdesc.
__global__ __launch_bounds__(256) void bin_kernel(const int* __restrict__ ei,
                                                  unsigned* __restrict__ ebuf,
                                                  int* __restrict__ bcnt,
                                                  float* __restrict__ stats,
                                                  float* __restrict__ gdesc) {
    __shared__ unsigned lbin[NBK][LCAP];
    __shared__ int lcnt[NBK];
    int t = threadIdx.x;
    int gt = blockIdx.x * 256 + t;
    int total = gridDim.x * 256;
    for (int i = gt; i < NL * 256; i += total) stats[i] = 0.f;
    for (int i = gt; i < NG * GD_COLS; i += total) gdesc[i] = 0.f;
    for (int b = t; b < NBK; b += 256) lcnt[b] = 0;
    __syncthreads();
    int base = blockIdx.x * 4096;
#pragma unroll
    for (int i = 0; i < 16; ++i) {
        int e = base + i * 256 + t;
        if (e < NE) {
            int s = ei[e];
            int d = ei[NE + e];
            int bkt = d >> 8;
            unsigned enc = (unsigned)s | ((unsigned)(d & 255) << 16);
            int pos = atomicAdd(&lcnt[bkt], 1);
            if (pos < LCAP) lbin[bkt][pos] = enc;
            else {  // astronomically rare LDS-bin overflow: append direct to global
                int gpos = atomicAdd(&bcnt[bkt], 1);
                if (gpos < CAPB) ebuf[(size_t)bkt * CAPB + gpos] = enc;
            }
        }
    }
    __syncthreads();
    int lane = t & 63, wid = t >> 6;
    for (int bkt = wid; bkt < NBK; bkt += 4) {
        int n = lcnt[bkt];
        if (n > LCAP) n = LCAP;
        int gbase = 0;
        if (lane == 0 && n > 0) gbase = atomicAdd(&bcnt[bkt], n);
        gbase = __shfl(gbase, 0);
        for (int wq = lane; wq < n; wq += 64) {
            int gp = gbase + wq;
            if (gp < CAPB) ebuf[(size_t)bkt * CAPB + gp] = lbin[bkt][wq];
        }
    }
}

// ---------------- edge-table build, pass B: per-bucket LDS table + coalesced store ----
// One block per bucket (256 dst nodes). Builds cnt + 64-slot ssrc rows in LDS, then
// writes the 32 KB ssrc stripe with full-line dwordx4 stores. Stale slots are uninit
// LDS -> u16 <= 65535: reads stay in-workspace and are deg-masked downstream.
__global__ __launch_bounds__(256) void fill_kernel(const unsigned* __restrict__ ebuf,
                                                   const int* __restrict__ bcnt,
                                                   int* __restrict__ cnt,
                                                   unsigned short* __restrict__ ssrc) {
    __shared__ int c256[256];
    __shared__ uiv4 tblv[2048];  // 256 nodes x 64 ushort slots = 32 KB
    unsigned short* tbl = (unsigned short*)tblv;
    int t = threadIdx.x;
    int b = blockIdx.x;
    c256[t] = 0;
    __syncthreads();
    int blen = bcnt[b];
    if (blen > CAPB) blen = CAPB;
    for (int i = t; i < blen; i += 256) {
        unsigned e = ebuf[(size_t)b * CAPB + i];
        int dlo = e >> 16;
        int pos = atomicAdd(&c256[dlo], 1);
        if (pos < 64) tbl[dlo * 64 + pos] = (unsigned short)(e & 0xffffu);
    }
    __syncthreads();
    int nb = b << 8;
    if (nb + t < NN) cnt[nb + t] = c256[t];
    uiv4* dst = (uiv4*)&ssrc[(size_t)nb << 6];
    for (int i = t; i < 2048; i += 256) {
        int node = nb + (i >> 3);
        if (node < NN) dst[i] = tblv[i];
    }
}

// ---------------- layer 0: gather0 + rank-1 expand + stats0 + first_desc ----------------
__global__ __launch_bounds__(256) void layer0_kernel(
    const float* __restrict__ x, const int* __restrict__ cnt,
    const unsigned short* __restrict__ ssrc, const float* __restrict__ w,
    const float* __restrict__ bias, const int* __restrict__ batch, float* __restrict__ gdesc,
    bf16_t* __restrict__ y, float* __restrict__ stats) {
    __shared__ float z0p[256];
    __shared__ float z0s[64];
    int t = threadIdx.x, lane = t & 63, wid = t >> 6;
    int r0 = blockIdx.x * 64;
    if (t < 64) {
        int i = r0 + t;
        if (i < NN) atomicAdd(&gdesc[batch[i] * GD_COLS], x[i]);
    }
    {
        int node = t >> 2, sub = t & 3;
        int i = r0 + node;
        float acc = 0.f;
        if (i < NN) {
            int deg = cnt[i];
            if (deg > DEG_CAP) deg = DEG_CAP;
            int pa = i << 6;
            for (int p = sub; p < deg; p += 4) acc += x[ssrc[pa + p]];
            if (sub == 0) acc += x[i];
        }
        z0p[t] = acc;
    }
    __syncthreads();
    if (t < 64) z0s[t] = z0p[4 * t] + z0p[4 * t + 1] + z0p[4 * t + 2] + z0p[4 * t + 3];
    __syncthreads();
    float wv = w[lane], bv = bias[lane];
    float s = 0.f, s2 = 0.f;
    for (int j = 0; j < 16; ++j) {
        int r = r0 + wid * 16 + j;
        if (r < NN) {
            float v = z0s[wid * 16 + j] * wv + bv;
            y[r * HC + lane] = f2bf(v);
            s += v;
            s2 += v * v;
        }
    }
    __shared__ float ls[256], ls2[256];
    ls[t] = s;
    ls2[t] = s2;
    __syncthreads();
    if (wid == 0) {
        float ts = ls[lane] + ls[64 + lane] + ls[128 + lane] + ls[192 + lane];
        float t2 = ls2[lane] + ls2[64 + lane] + ls2[128 + lane] + ls2[192 + lane];
        atomicAdd(&stats[lane], ts);
        atomicAdd(&stats[64 + lane], t2);
    }
}

// ---------------- K1: BN2(prev)+ReLU fused gather + gdesc(prev) + MFMA GEMM1 + stats1 ----
__global__ __launch_bounds__(512, 2) void gather_gemm_kernel(
    const bf16_t* __restrict__ u, const float* __restrict__ statsPrev,
    const float* __restrict__ gPrev, const float* __restrict__ bPrev,
    const int* __restrict__ cnt, const unsigned short* __restrict__ ssrc,
    const float* __restrict__ w, const float* __restrict__ bias, const int* __restrict__ batch,
    float* __restrict__ gdesc, int layerPrev, bf16_t* __restrict__ out,
    float* __restrict__ statsOut) {
    __shared__ unsigned zw[64 * 33];
    __shared__ unsigned wsm[64 * 33];
    __shared__ float a1[64], s1[64];
    __shared__ float redS[8][64], redQ[8][64];
    int t = threadIdx.x, lane = t & 63, wid = t >> 6;
    int r0 = blockIdx.x * 64;
    // --- hoisted Phase-B index + self-row fetch ---
    int li = lane & 7;       // channel slice owner
    int gq = lane >> 3;      // row within wave's 8
    int gbase = lane & 56;   // first lane of this 8-lane group
    int nB = r0 + wid * 8 + gq;
    uiv4 myidx;
    myidx[0] = 0; myidx[1] = 0; myidx[2] = 0; myidx[3] = 0;
    uiv4 selfv;
    selfv[0] = 0; selfv[1] = 0; selfv[2] = 0; selfv[3] = 0;
    int degB = 0;
    if (nB < NN) {
        degB = cnt[nB];
        if (degB > DEG_CAP) degB = DEG_CAP;
        myidx = *(const uiv4*)&ssrc[((size_t)nB << 6) + li * 8];
        selfv = *(const uiv4*)&u[(size_t)nB * HC + li * 8];
    }
    if (t < 64) {
        float mu = statsPrev[t] * (1.0f / NN);
        float var = statsPrev[64 + t] * (1.0f / NN) - mu * mu;
        float a = gPrev[t] * rsqrtf(var + BN_EPS);
        a1[t] = a;
        s1[t] = bPrev[t] - mu * a;
    }
    for (int idx = t; idx < 2048; idx += 512) {
        int kk = idx >> 6, c = idx & 63;
        unsigned lo = f2bfbits(w[(2 * kk) * 64 + c]);
        unsigned hi = f2bfbits(w[(2 * kk + 1) * 64 + c]);
        wsm[c * 33 + kk] = lo | (hi << 16);
    }
    __syncthreads();
    // Phase B: self-term init + edge gather (8-lane groups, shfl-broadcast indices)
    {
        float a8[8], s8[8];
#pragma unroll
        for (int c = 0; c < 8; ++c) {
            a8[c] = a1[li * 8 + c];
            s8[c] = s1[li * 8 + c];
        }
        float acc[8];
        if (nB < NN) {
            acc[0] = fmaxf(bflo(selfv[0]) * a8[0] + s8[0], 0.f);
            acc[1] = fmaxf(bfhi(selfv[0]) * a8[1] + s8[1], 0.f);
            acc[2] = fmaxf(bflo(selfv[1]) * a8[2] + s8[2], 0.f);
            acc[3] = fmaxf(bfhi(selfv[1]) * a8[3] + s8[3], 0.f);
            acc[4] = fmaxf(bflo(selfv[2]) * a8[4] + s8[4], 0.f);
            acc[5] = fmaxf(bfhi(selfv[2]) * a8[5] + s8[5], 0.f);
            acc[6] = fmaxf(bflo(selfv[3]) * a8[6] + s8[6], 0.f);
            acc[7] = fmaxf(bfhi(selfv[3]) * a8[7] + s8[7], 0.f);
        } else {
#pragma unroll
            for (int c = 0; c < 8; ++c) acc[c] = 0.f;
        }
        if (degB > 0) {
            uiv4 rv[8];
            int cntA = degB < 8 ? degB : 8;
            {
                unsigned w0 = __shfl(myidx[0], gbase);
                unsigned w1 = __shfl(myidx[1], gbase);
                unsigned w2 = __shfl(myidx[2], gbase);
                unsigned w3 = __shfl(myidx[3], gbase);
                int id[8] = {(int)(w0 & 0xffff), (int)(w0 >> 16), (int)(w1 & 0xffff),
                             (int)(w1 >> 16),    (int)(w2 & 0xffff), (int)(w2 >> 16),
                             (int)(w3 & 0xffff), (int)(w3 >> 16)};
#pragma unroll
                for (int e = 0; e < 8; ++e)
                    rv[e] = *(const uiv4*)&u[(size_t)id[e] * HC + li * 8];
            }
            for (int b = 1; cntA > 0; ++b) {
                uiv4 nv[8];
                int cntB = 0;
                if (b * 8 < degB) {
                    unsigned w0 = __shfl(myidx[0], gbase + b);
                    unsigned w1 = __shfl(myidx[1], gbase + b);
                    unsigned w2 = __shfl(myidx[2], gbase + b);
                    unsigned w3 = __shfl(myidx[3], gbase + b);
                    int id[8] = {(int)(w0 & 0xffff), (int)(w0 >> 16), (int)(w1 & 0xffff),
                                 (int)(w1 >> 16),    (int)(w2 & 0xffff), (int)(w2 >> 16),
                                 (int)(w3 & 0xffff), (int)(w3 >> 16)};
#pragma unroll
                    for (int e = 0; e < 8; ++e)
                        nv[e] = *(const uiv4*)&u[(size_t)id[e] * HC + li * 8];
                    cntB = degB - b * 8;
                    if (cntB > 8) cntB = 8;
                }
#pragma unroll
                for (int e = 0; e < 8; ++e) {
                    float v0 = fmaxf(bflo(rv[e][0]) * a8[0] + s8[0], 0.f);
                    float v1 = fmaxf(bfhi(rv[e][0]) * a8[1] + s8[1], 0.f);
                    float v2 = fmaxf(bflo(rv[e][1]) * a8[2] + s8[2], 0.f);
                    float v3 = fmaxf(bfhi(rv[e][1]) * a8[3] + s8[3], 0.f);
                    float v4 = fmaxf(bflo(rv[e][2]) * a8[4] + s8[4], 0.f);
                    float v5 = fmaxf(bfhi(rv[e][2]) * a8[5] + s8[5], 0.f);
                    float v6 = fmaxf(bflo(rv[e][3]) * a8[6] + s8[6], 0.f);
                    float v7 = fmaxf(bfhi(rv[e][3]) * a8[7] + s8[7], 0.f);
                    if (e < cntA) {
                        acc[0] += v0;
                        acc[1] += v1;
                        acc[2] += v2;
                        acc[3] += v3;
                        acc[4] += v4;
                        acc[5] += v5;
                        acc[6] += v6;
                        acc[7] += v7;
                    }
                }
#pragma unroll
                for (int e = 0; e < 8; ++e) rv[e] = nv[e];
                cntA = cntB;
            }
        }
        // pack z to bf16 pairs; OOB rows store zeros (acc==0)
        int lr = wid * 8 + gq;
        unsigned* zp = &zw[lr * 33 + li * 4];
        zp[0] = f2bfbits(acc[0]) | (f2bfbits(acc[1]) << 16);
        zp[1] = f2bfbits(acc[2]) | (f2bfbits(acc[3]) << 16);
        zp[2] = f2bfbits(acc[4]) | (f2bfbits(acc[5]) << 16);
        zp[3] = f2bfbits(acc[6]) | (f2bfbits(acc[7]) << 16);
    }
    // Phase A: gdesc segmented sum only (lane = channel); overlaps the pre-MFMA barrier
    {
        float av = a1[lane], sv = s1[lane];
        int col = 1 + layerPrev * HC + lane;
        float gacc = 0.f;
        int cur = -1;
        for (int j = 0; j < 8; ++j) {
            int gr = r0 + wid * 8 + j;
            if (gr < NN) {
                float hv = fmaxf(bf2f(u[(size_t)gr * HC + lane]) * av + sv, 0.f);
                int gid = batch[gr];
                if (gid != cur) {
                    if (cur >= 0) atomicAdd(&gdesc[cur * GD_COLS + col], gacc);
                    cur = gid;
                    gacc = 0.f;
                }
                gacc += hv;
            }
        }
        if (cur >= 0) atomicAdd(&gdesc[cur * GD_COLS + col], gacc);
    }
    __syncthreads();  // zw rows cross waves for MFMA A-frags
    mfma_gemm_phase(zw, wsm, bias, out, statsOut, redS, redQ, r0, t, lane, wid);
}

// ---------------- K2: BN1+ReLU staging + MFMA GEMM2 + stats2 (64 rows/block) ----------
__global__ __launch_bounds__(512) void gemm64_norm_kernel(
    const bf16_t* __restrict__ in, const float* __restrict__ w, const float* __restrict__ bias,
    const float* __restrict__ statsIn, const float* __restrict__ gIn,
    const float* __restrict__ bIn, bf16_t* __restrict__ out, float* __restrict__ statsOut) {
    __shared__ unsigned zw[64 * 33];
    __shared__ unsigned wsm[64 * 33];
    __shared__ float a1[64], s1[64];
    __shared__ float redS[8][64], redQ[8][64];
    int t = threadIdx.x, lane = t & 63, wid = t >> 6;
    int r0 = blockIdx.x * 64;
    if (t < 64) {
        float mu = statsIn[t] * (1.0f / NN);
        float var = statsIn[64 + t] * (1.0f / NN) - mu * mu;
        float a = gIn[t] * rsqrtf(var + BN_EPS);
        a1[t] = a;
        s1[t] = bIn[t] - mu * a;
    }
    for (int idx = t; idx < 2048; idx += 512) {
        int kk = idx >> 6, c = idx & 63;
        unsigned lo = f2bfbits(w[(2 * kk) * 64 + c]);
        unsigned hi = f2bfbits(w[(2 * kk + 1) * 64 + c]);
        wsm[c * 33 + kk] = lo | (hi << 16);
    }
    __syncthreads();
    for (int idx = t; idx < 2048; idx += 512) {
        int r = idx >> 5, kk = idx & 31;
        int gr = r0 + r;
        unsigned zword = 0u;
        if (gr < NN) {
            unsigned word = *(const unsigned*)&in[(size_t)gr * HC + 2 * kk];
            float v0 = fmaxf(bflo(word) * a1[2 * kk] + s1[2 * kk], 0.f);
            float v1 = fmaxf(bfhi(word) * a1[2 * kk + 1] + s1[2 * kk + 1], 0.f);
            zword = f2bfbits(v0) | (f2bfbits(v1) << 16);
        }
        zw[r * 33 + kk] = zword;
    }
    __syncthreads();
    mfma_gemm_phase(zw, wsm, bias, out, statsOut, redS, redQ, r0, t, lane, wid);
}

// ---------------- last-layer gdesc (BN2+ReLU, segmented sum, no h write) ----------------
#define CHK 16
__global__ void gdesc_last_kernel(const bf16_t* __restrict__ u, const float* __restrict__ stats,
                                  const float* __restrict__ g, const float* __restrict__ b,
                                  const int* __restrict__ batch, float* __restrict__ gdesc,
                                  int layer) {
    int lane = threadIdx.x & 63;
    int wid = threadIdx.x >> 6;
    int i0 = (blockIdx.x * 4 + wid) * CHK;
    if (i0 >= NN) return;
    float mu = stats[lane] * (1.0f / NN);
    float var = stats[64 + lane] * (1.0f / NN) - mu * mu;
    float a = g[lane] * rsqrtf(var + BN_EPS);
    float s = b[lane] - mu * a;
    int col = 1 + layer * HC + lane;
    float acc = 0.f;
    int cur = -1;
    int iend = i0 + CHK;
    if (iend > NN) iend = NN;
    for (int i = i0; i < iend; ++i) {
        int gid = batch[i];
        if (gid != cur) {
            if (cur >= 0) atomicAdd(&gdesc[cur * GD_COLS + col], acc);
            cur = gid;
            acc = 0.f;
        }
        acc += fmaxf(bf2f(u[i * HC + lane]) * a + s, 0.f);
    }
    if (cur >= 0) atomicAdd(&gdesc[cur * GD_COLS + col], acc);
}

__global__ void final_gemm_kernel(const float* __restrict__ gdesc, const float* __restrict__ lw,
                                  const float* __restrict__ lb, float* __restrict__ out) {
    int g = blockIdx.x;
    int lane = threadIdx.x;
    float a0 = 0.f, a1 = 0.f;
    for (int j = lane; j < GD_COLS; j += 64) {
        float v = gdesc[g * GD_COLS + j];
        a0 += v * lw[j * 2 + 0];
        a1 += v * lw[j * 2 + 1];
    }
    for (int off = 32; off > 0; off >>= 1) {
        a0 += __shfl_down(a0, off);
        a1 += __shfl_down(a1, off);
    }
    if (lane == 0) {
        out[g * 2 + 0] = a0 + lb[0];
        out[g * 2 + 1] = a1 + lb[1];
    }
}

extern "C" void kernel_launch(void* const* d_in, const int* in_sizes, int n_in, void* d_out,
                              int out_size, void* d_ws, size_t ws_size, hipStream_t stream) {
    const float* x = (const float*)d_in[0];
    const int* ei = (const int*)d_in[1];
    const int* batch = (const int*)d_in[2];
    const float* w1_0 = (const float*)d_in[3];
    const float* w1_rest = (const float*)d_in[4];
    const float* b1 = (const float*)d_in[5];
    const float* gm = (const float*)d_in[6];
    const float* bm = (const float*)d_in[7];
    const float* w2 = (const float*)d_in[8];
    const float* b2 = (const float*)d_in[9];
    const float* go = (const float*)d_in[10];
    const float* bo = (const float*)d_in[11];
    const float* lw = (const float*)d_in[12];
    const float* lb = (const float*)d_in[13];
    float* out = (float*)d_out;

    float* stats = (float*)d_ws;                     // NL*256
    float* gdesc = stats + NL * 256;                 // NG*321
    bf16_t* ybuf = (bf16_t*)(gdesc + (size_t)NG * GD_COLS + 64);  // NN*64 bf16
    bf16_t* ubuf = ybuf + (size_t)NN * HC;           // NN*64 bf16
    int* cnt = (int*)(ubuf + (size_t)NN * HC);       // NN
    unsigned short* ssrc = (unsigned short*)(cnt + NN);  // NN*64 ushort
    int* bcnt = (int*)(ssrc + (size_t)NN * 64);      // NBK
    // ebuf (4 MB) aliases ybuf: consumed by fill_kernel before layer0 writes ybuf
    unsigned* ebuf = (unsigned*)ybuf;

    hipMemsetAsync(bcnt, 0, NBK * sizeof(int), stream);

    bin_kernel<<<(NE + 4095) / 4096, 256, 0, stream>>>(ei, ebuf, bcnt, stats, gdesc);
    fill_kernel<<<NBK, 256, 0, stream>>>(ebuf, bcnt, cnt, ssrc);

    layer0_kernel<<<(NN + 63) / 64, 256, 0, stream>>>(x, cnt, ssrc, w1_0, b1, batch, gdesc, ybuf,
                                                      stats);
    gemm64_norm_kernel<<<(NN + 63) / 64, 512, 0, stream>>>(ybuf, w2, b2, stats, gm, bm, ubuf,
                                                           stats + 128);
    for (int l = 1; l < NL; ++l) {
        float* st1 = stats + l * 256;
        float* st2 = st1 + 128;
        float* stPrev = stats + (l - 1) * 256 + 128;
        gather_gemm_kernel<<<(NN + 63) / 64, 512, 0, stream>>>(
            ubuf, stPrev, go + (l - 1) * HC, bo + (l - 1) * HC, cnt, ssrc,
            w1_rest + (size_t)(l - 1) * HC * HC, b1 + l * HC, batch, gdesc, l - 1, ybuf, st1);
        gemm64_norm_kernel<<<(NN + 63) / 64, 512, 0, stream>>>(
            ybuf, w2 + (size_t)l * HC * HC, b2 + l * HC, st1, gm + l * HC, bm + l * HC, ubuf, st2);
    }
    gdesc_last_kernel<<<(NN + 4 * CHK - 1) / (4 * CHK), 256, 0, stream>>>(
        ubuf, stats + 4 * 256 + 128, go + 4 * HC, bo + 4 * HC, batch, gdesc, 4);
    final_gemm_kernel<<<NG, 64, 0, stream>>>(gdesc, lw, lb, out);
}

// Round 6
// 446.275 us; speedup vs baseline: 1.3535x; 1.3535x over previous
//
#include <hip/hip_runtime.h>

#define NN 50000
#define NE 800000
#define NG 512
#define HC 64
#define NL 5
#define GD_COLS 321
#define BN_EPS 1e-5f
#define DEG_CAP 64  // max degree: Poisson(16), P(>64) ~ 1e-18 — fixed-stride edge table

#define SLICE 6250   // NN/8: destination slice per XCD group
#define ECHUNK 3125  // NE/256: edge chunk per block pair-group

typedef unsigned short bf16_t;
typedef unsigned int uiv4 __attribute__((ext_vector_type(4)));
typedef __attribute__((ext_vector_type(8))) short short8v;   // 8 bf16 = 4 VGPRs (MFMA A/B frag)
typedef __attribute__((ext_vector_type(4))) float f32x4;     // MFMA C/D frag
typedef __attribute__((ext_vector_type(4))) unsigned uint4v;

static __device__ __forceinline__ unsigned f2bfbits(float f) {
    unsigned u = __float_as_uint(f);
    return (u + 0x7FFFu + ((u >> 16) & 1u)) >> 16;
}
static __device__ __forceinline__ bf16_t f2bf(float f) { return (bf16_t)f2bfbits(f); }
static __device__ __forceinline__ float bf2f(bf16_t h) {
    return __uint_as_float(((unsigned)h) << 16);
}
static __device__ __forceinline__ float bflo(unsigned w) { return __uint_as_float(w << 16); }
static __device__ __forceinline__ float bfhi(unsigned w) {
    return __uint_as_float(w & 0xffff0000u);
}

// ---- shared MFMA GEMM phase: OUT[64x64] = ZW[64x64] @ WSM[64x64] + bias, + per-channel stats.
// zw: packed bf16 pairs, row-major [64 rows][33 words] (word kk = z[2kk],z[2kk+1]).
// wsm: packed bf16 pairs of W by column: wsm[c*33+kk] = (W[2kk][c], W[2kk+1][c]).
// Wave wid owns output tiles (tr=wid>>1, tc = (wid&1)*2 (+1)).
// A-frag: lane holds A[tr*16+(l&15)][kc*32+8*(l>>4)+0..7] (contiguous-k, m97/m201 layout).
// C/D: col=lane&15, row=(lane>>4)*4+j (m89-verified).
static __device__ __forceinline__ void mfma_gemm_phase(
    const unsigned* zw, const unsigned* wsm, const float* __restrict__ bias,
    bf16_t* __restrict__ out, float* __restrict__ statsOut, float (*redS)[64],
    float (*redQ)[64], int r0, int t, int lane, int wid) {
    int l15 = lane & 15, l4 = lane >> 4;
    int tr = wid >> 1;
    int tc0 = (wid & 1) * 2;
    f32x4 d0 = {0.f, 0.f, 0.f, 0.f}, d1 = {0.f, 0.f, 0.f, 0.f};
    const unsigned* arow = &zw[(tr * 16 + l15) * 33];
    const unsigned* brow0 = &wsm[(tc0 * 16 + l15) * 33];
    const unsigned* brow1 = &wsm[((tc0 + 1) * 16 + l15) * 33];
#pragma unroll
    for (int kc = 0; kc < 2; ++kc) {
        int kb = kc * 16 + l4 * 4;
        uint4v aw = {arow[kb], arow[kb + 1], arow[kb + 2], arow[kb + 3]};
        uint4v bw0 = {brow0[kb], brow0[kb + 1], brow0[kb + 2], brow0[kb + 3]};
        uint4v bw1 = {brow1[kb], brow1[kb + 1], brow1[kb + 2], brow1[kb + 3]};
        short8v af = __builtin_bit_cast(short8v, aw);
        d0 = __builtin_amdgcn_mfma_f32_16x16x32_bf16(af, __builtin_bit_cast(short8v, bw0), d0,
                                                     0, 0, 0);
        d1 = __builtin_amdgcn_mfma_f32_16x16x32_bf16(af, __builtin_bit_cast(short8v, bw1), d1,
                                                     0, 0, 0);
    }
    int c0 = tc0 * 16 + l15, c1 = c0 + 16;
    float bv0 = bias[c0], bv1 = bias[c1];
    float s0 = 0.f, q0 = 0.f, s1 = 0.f, q1 = 0.f;
#pragma unroll
    for (int j = 0; j < 4; ++j) {
        int gr = r0 + tr * 16 + l4 * 4 + j;
        if (gr < NN) {
            float v0 = d0[j] + bv0, v1 = d1[j] + bv1;
            out[(size_t)gr * HC + c0] = f2bf(v0);
            out[(size_t)gr * HC + c1] = f2bf(v1);
            s0 += v0;
            q0 += v0 * v0;
            s1 += v1;
            q1 += v1 * v1;
        }
    }
    // fold the 4 lanes (l>>4 groups) that share a column
    s0 += __shfl_xor(s0, 16); s0 += __shfl_xor(s0, 32);
    q0 += __shfl_xor(q0, 16); q0 += __shfl_xor(q0, 32);
    s1 += __shfl_xor(s1, 16); s1 += __shfl_xor(s1, 32);
    q1 += __shfl_xor(q1, 16); q1 += __shfl_xor(q1, 32);
    // wave covers channels [tc0*16, tc0*16+32); zero-fill the other 32 for the block reduce
    if (l4 == 0) { redS[wid][c0] = s0; redQ[wid][c0] = q0; }
    else if (l4 == 1) { redS[wid][c1] = s1; redQ[wid][c1] = q1; }
    else if (l4 == 2) { redS[wid][c0 ^ 32] = 0.f; redQ[wid][c0 ^ 32] = 0.f; }
    else { redS[wid][c1 ^ 32] = 0.f; redQ[wid][c1 ^ 32] = 0.f; }
    __syncthreads();
    if (t < 64) {
        float ts = 0.f, t2 = 0.f;
#pragma unroll
        for (int k = 0; k < 8; ++k) {
            ts += redS[k][t];
            t2 += redQ[k][t];
        }
        atomicAdd(&statsOut[t], ts);
        atomicAdd(&statsOut[64 + t], t2);
    }
}

// ---------------- edge table build: XCD-sliced scatter + scratch zeroing ----------------
// grid = 256 chunks x 8 groups. g = blockIdx&7 ~ XCD id (default round-robin dispatch).
// Group g only handles destinations in [g*SLICE, (g+1)*SLICE): all cnt/ssrc stores from
// one XCD target an 800 KB slice resident in that XCD's L2 -> lines re-dirtied ~8x
// before one write-back (kills the 45 MB scattered-store write amplification).
// Edge list is scanned 8x (once per group); re-reads are L3 hits. Correctness does not
// depend on the blockIdx<->XCD mapping — only locality does.
__global__ __launch_bounds__(256) void scatter_kernel(const int* __restrict__ ei,
                                                      int* __restrict__ cnt,
                                                      unsigned short* __restrict__ ssrc,
                                                      float* __restrict__ stats,
                                                      float* __restrict__ gdesc) {
    int t = threadIdx.x;
    int g = blockIdx.x & 7;
    int c = blockIdx.x >> 3;
    int gt = blockIdx.x * 256 + t;
    int total = gridDim.x * 256;
    // zero stats + gdesc (consumed by later dispatches only)
    for (int i = gt; i < NL * 256; i += total) stats[i] = 0.f;
    for (int i = gt; i < NG * GD_COLS; i += total) gdesc[i] = 0.f;
    int lo = g * SLICE, hi = lo + SLICE;
    int e0 = c * ECHUNK;
    int e1 = e0 + ECHUNK;
    if (e1 > NE) e1 = NE;
    for (int e = e0 + t; e < e1; e += 256) {
        int d = ei[NE + e];
        if (d >= lo && d < hi) {
            int s = ei[e];
            int pos = atomicAdd(&cnt[d], 1);
            if (pos < DEG_CAP) ssrc[(d << 6) + pos] = (unsigned short)s;
        }
    }
}

// ---------------- layer 0: gather0 + rank-1 expand + stats0 + first_desc ----------------
__global__ __launch_bounds__(256) void layer0_kernel(
    const float* __restrict__ x, const int* __restrict__ cnt,
    const unsigned short* __restrict__ ssrc, const float* __restrict__ w,
    const float* __restrict__ bias, const int* __restrict__ batch, float* __restrict__ gdesc,
    bf16_t* __restrict__ y, float* __restrict__ stats) {
    __shared__ float z0p[256];
    __shared__ float z0s[64];
    int t = threadIdx.x, lane = t & 63, wid = t >> 6;
    int r0 = blockIdx.x * 64;
    if (t < 64) {
        int i = r0 + t;
        if (i < NN) atomicAdd(&gdesc[batch[i] * GD_COLS], x[i]);
    }
    {
        int node = t >> 2, sub = t & 3;
        int i = r0 + node;
        float acc = 0.f;
        if (i < NN) {
            int deg = cnt[i];
            if (deg > DEG_CAP) deg = DEG_CAP;
            int pa = i << 6;
            for (int p = sub; p < deg; p += 4) acc += x[ssrc[pa + p]];
            if (sub == 0) acc += x[i];
        }
        z0p[t] = acc;
    }
    __syncthreads();
    if (t < 64) z0s[t] = z0p[4 * t] + z0p[4 * t + 1] + z0p[4 * t + 2] + z0p[4 * t + 3];
    __syncthreads();
    float wv = w[lane], bv = bias[lane];
    float s = 0.f, s2 = 0.f;
    for (int j = 0; j < 16; ++j) {
        int r = r0 + wid * 16 + j;
        if (r < NN) {
            float v = z0s[wid * 16 + j] * wv + bv;
            y[r * HC + lane] = f2bf(v);
            s += v;
            s2 += v * v;
        }
    }
    __shared__ float ls[256], ls2[256];
    ls[t] = s;
    ls2[t] = s2;
    __syncthreads();
    if (wid == 0) {
        float ts = ls[lane] + ls[64 + lane] + ls[128 + lane] + ls[192 + lane];
        float t2 = ls2[lane] + ls2[64 + lane] + ls2[128 + lane] + ls2[192 + lane];
        atomicAdd(&stats[lane], ts);
        atomicAdd(&stats[64 + lane], t2);
    }
}

// ---------------- K1: BN2(prev)+ReLU fused gather + gdesc(prev) + MFMA GEMM1 + stats1 ----
__global__ __launch_bounds__(512, 2) void gather_gemm_kernel(
    const bf16_t* __restrict__ u, const float* __restrict__ statsPrev,
    const float* __restrict__ gPrev, const float* __restrict__ bPrev,
    const int* __restrict__ cnt, const unsigned short* __restrict__ ssrc,
    const float* __restrict__ w, const float* __restrict__ bias, const int* __restrict__ batch,
    float* __restrict__ gdesc, int layerPrev, bf16_t* __restrict__ out,
    float* __restrict__ statsOut) {
    __shared__ unsigned zw[64 * 33];
    __shared__ unsigned wsm[64 * 33];
    __shared__ float a1[64], s1[64];
    __shared__ float redS[8][64], redQ[8][64];
    int t = threadIdx.x, lane = t & 63, wid = t >> 6;
    int r0 = blockIdx.x * 64;
    // --- hoisted Phase-B index + self-row fetch ---
    int li = lane & 7;       // channel slice owner
    int gq = lane >> 3;      // row within wave's 8
    int gbase = lane & 56;   // first lane of this 8-lane group
    int nB = r0 + wid * 8 + gq;
    uiv4 myidx;
    myidx[0] = 0; myidx[1] = 0; myidx[2] = 0; myidx[3] = 0;
    uiv4 selfv;
    selfv[0] = 0; selfv[1] = 0; selfv[2] = 0; selfv[3] = 0;
    int degB = 0;
    if (nB < NN) {
        degB = cnt[nB];
        if (degB > DEG_CAP) degB = DEG_CAP;
        myidx = *(const uiv4*)&ssrc[((size_t)nB << 6) + li * 8];
        selfv = *(const uiv4*)&u[(size_t)nB * HC + li * 8];
    }
    if (t < 64) {
        float mu = statsPrev[t] * (1.0f / NN);
        float var = statsPrev[64 + t] * (1.0f / NN) - mu * mu;
        float a = gPrev[t] * rsqrtf(var + BN_EPS);
        a1[t] = a;
        s1[t] = bPrev[t] - mu * a;
    }
    for (int idx = t; idx < 2048; idx += 512) {
        int kk = idx >> 6, c = idx & 63;
        unsigned lo = f2bfbits(w[(2 * kk) * 64 + c]);
        unsigned hi = f2bfbits(w[(2 * kk + 1) * 64 + c]);
        wsm[c * 33 + kk] = lo | (hi << 16);
    }
    __syncthreads();
    // Phase B: self-term init + edge gather (8-lane groups, shfl-broadcast indices)
    {
        float a8[8], s8[8];
#pragma unroll
        for (int c = 0; c < 8; ++c) {
            a8[c] = a1[li * 8 + c];
            s8[c] = s1[li * 8 + c];
        }
        float acc[8];
        if (nB < NN) {
            acc[0] = fmaxf(bflo(selfv[0]) * a8[0] + s8[0], 0.f);
            acc[1] = fmaxf(bfhi(selfv[0]) * a8[1] + s8[1], 0.f);
            acc[2] = fmaxf(bflo(selfv[1]) * a8[2] + s8[2], 0.f);
            acc[3] = fmaxf(bfhi(selfv[1]) * a8[3] + s8[3], 0.f);
            acc[4] = fmaxf(bflo(selfv[2]) * a8[4] + s8[4], 0.f);
            acc[5] = fmaxf(bfhi(selfv[2]) * a8[5] + s8[5], 0.f);
            acc[6] = fmaxf(bflo(selfv[3]) * a8[6] + s8[6], 0.f);
            acc[7] = fmaxf(bfhi(selfv[3]) * a8[7] + s8[7], 0.f);
        } else {
#pragma unroll
            for (int c = 0; c < 8; ++c) acc[c] = 0.f;
        }
        if (degB > 0) {
            uiv4 rv[8];
            int cntA = degB < 8 ? degB : 8;
            {
                unsigned w0 = __shfl(myidx[0], gbase);
                unsigned w1 = __shfl(myidx[1], gbase);
                unsigned w2 = __shfl(myidx[2], gbase);
                unsigned w3 = __shfl(myidx[3], gbase);
                int id[8] = {(int)(w0 & 0xffff), (int)(w0 >> 16), (int)(w1 & 0xffff),
                             (int)(w1 >> 16),    (int)(w2 & 0xffff), (int)(w2 >> 16),
                             (int)(w3 & 0xffff), (int)(w3 >> 16)};
#pragma unroll
                for (int e = 0; e < 8; ++e)
                    rv[e] = *(const uiv4*)&u[(size_t)id[e] * HC + li * 8];
            }
            for (int b = 1; cntA > 0; ++b) {
                uiv4 nv[8];
                int cntB = 0;
                if (b * 8 < degB) {
                    unsigned w0 = __shfl(myidx[0], gbase + b);
                    unsigned w1 = __shfl(myidx[1], gbase + b);
                    unsigned w2 = __shfl(myidx[2], gbase + b);
                    unsigned w3 = __shfl(myidx[3], gbase + b);
                    int id[8] = {(int)(w0 & 0xffff), (int)(w0 >> 16), (int)(w1 & 0xffff),
                                 (int)(w1 >> 16),    (int)(w2 & 0xffff), (int)(w2 >> 16),
                                 (int)(w3 & 0xffff), (int)(w3 >> 16)};
#pragma unroll
                    for (int e = 0; e < 8; ++e)
                        nv[e] = *(const uiv4*)&u[(size_t)id[e] * HC + li * 8];
                    cntB = degB - b * 8;
                    if (cntB > 8) cntB = 8;
                }
#pragma unroll
                for (int e = 0; e < 8; ++e) {
                    float v0 = fmaxf(bflo(rv[e][0]) * a8[0] + s8[0], 0.f);
                    float v1 = fmaxf(bfhi(rv[e][0]) * a8[1] + s8[1], 0.f);
                    float v2 = fmaxf(bflo(rv[e][1]) * a8[2] + s8[2], 0.f);
                    float v3 = fmaxf(bfhi(rv[e][1]) * a8[3] + s8[3], 0.f);
                    float v4 = fmaxf(bflo(rv[e][2]) * a8[4] + s8[4], 0.f);
                    float v5 = fmaxf(bfhi(rv[e][2]) * a8[5] + s8[5], 0.f);
                    float v6 = fmaxf(bflo(rv[e][3]) * a8[6] + s8[6], 0.f);
                    float v7 = fmaxf(bfhi(rv[e][3]) * a8[7] + s8[7], 0.f);
                    if (e < cntA) {
                        acc[0] += v0;
                        acc[1] += v1;
                        acc[2] += v2;
                        acc[3] += v3;
                        acc[4] += v4;
                        acc[5] += v5;
                        acc[6] += v6;
                        acc[7] += v7;
                    }
                }
#pragma unroll
                for (int e = 0; e < 8; ++e) rv[e] = nv[e];
                cntA = cntB;
            }
        }
        // pack z to bf16 pairs; OOB rows store zeros (acc==0)
        int lr = wid * 8 + gq;
        unsigned* zp = &zw[lr * 33 + li * 4];
        zp[0] = f2bfbits(acc[0]) | (f2bfbits(acc[1]) << 16);
        zp[1] = f2bfbits(acc[2]) | (f2bfbits(acc[3]) << 16);
        zp[2] = f2bfbits(acc[4]) | (f2bfbits(acc[5]) << 16);
        zp[3] = f2bfbits(acc[6]) | (f2bfbits(acc[7]) << 16);
    }
    // Phase A: gdesc segmented sum only (lane = channel); overlaps the pre-MFMA barrier
    {
        float av = a1[lane], sv = s1[lane];
        int col = 1 + layerPrev * HC + lane;
        float gacc = 0.f;
        int cur = -1;
        for (int j = 0; j < 8; ++j) {
            int gr = r0 + wid * 8 + j;
            if (gr < NN) {
                float hv = fmaxf(bf2f(u[(size_t)gr * HC + lane]) * av + sv, 0.f);
                int gid = batch[gr];
                if (gid != cur) {
                    if (cur >= 0) atomicAdd(&gdesc[cur * GD_COLS + col], gacc);
                    cur = gid;
                    gacc = 0.f;
                }
                gacc += hv;
            }
        }
        if (cur >= 0) atomicAdd(&gdesc[cur * GD_COLS + col], gacc);
    }
    __syncthreads();  // zw rows cross waves for MFMA A-frags
    mfma_gemm_phase(zw, wsm, bias, out, statsOut, redS, redQ, r0, t, lane, wid);
}

// ---------------- K2: BN1+ReLU staging + MFMA GEMM2 + stats2 (64 rows/block) ----------
__global__ __launch_bounds__(512) void gemm64_norm_kernel(
    const bf16_t* __restrict__ in, const float* __restrict__ w, const float* __restrict__ bias,
    const float* __restrict__ statsIn, const float* __restrict__ gIn,
    const float* __restrict__ bIn, bf16_t* __restrict__ out, float* __restrict__ statsOut) {
    __shared__ unsigned zw[64 * 33];
    __shared__ unsigned wsm[64 * 33];
    __shared__ float a1[64], s1[64];
    __shared__ float redS[8][64], redQ[8][64];
    int t = threadIdx.x, lane = t & 63, wid = t >> 6;
    int r0 = blockIdx.x * 64;
    if (t < 64) {
        float mu = statsIn[t] * (1.0f / NN);
        float var = statsIn[64 + t] * (1.0f / NN) - mu * mu;
        float a = gIn[t] * rsqrtf(var + BN_EPS);
        a1[t] = a;
        s1[t] = bIn[t] - mu * a;
    }
    for (int idx = t; idx < 2048; idx += 512) {
        int kk = idx >> 6, c = idx & 63;
        unsigned lo = f2bfbits(w[(2 * kk) * 64 + c]);
        unsigned hi = f2bfbits(w[(2 * kk + 1) * 64 + c]);
        wsm[c * 33 + kk] = lo | (hi << 16);
    }
    __syncthreads();
    for (int idx = t; idx < 2048; idx += 512) {
        int r = idx >> 5, kk = idx & 31;
        int gr = r0 + r;
        unsigned zword = 0u;
        if (gr < NN) {
            unsigned word = *(const unsigned*)&in[(size_t)gr * HC + 2 * kk];
            float v0 = fmaxf(bflo(word) * a1[2 * kk] + s1[2 * kk], 0.f);
            float v1 = fmaxf(bfhi(word) * a1[2 * kk + 1] + s1[2 * kk + 1], 0.f);
            zword = f2bfbits(v0) | (f2bfbits(v1) << 16);
        }
        zw[r * 33 + kk] = zword;
    }
    __syncthreads();
    mfma_gemm_phase(zw, wsm, bias, out, statsOut, redS, redQ, r0, t, lane, wid);
}

// ---------------- last-layer gdesc (BN2+ReLU, segmented sum, no h write) ----------------
#define CHK 16
__global__ void gdesc_last_kernel(const bf16_t* __restrict__ u, const float* __restrict__ stats,
                                  const float* __restrict__ g, const float* __restrict__ b,
                                  const int* __restrict__ batch, float* __restrict__ gdesc,
                                  int layer) {
    int lane = threadIdx.x & 63;
    int wid = threadIdx.x >> 6;
    int i0 = (blockIdx.x * 4 + wid) * CHK;
    if (i0 >= NN) return;
    float mu = stats[lane] * (1.0f / NN);
    float var = stats[64 + lane] * (1.0f / NN) - mu * mu;
    float a = g[lane] * rsqrtf(var + BN_EPS);
    float s = b[lane] - mu * a;
    int col = 1 + layer * HC + lane;
    float acc = 0.f;
    int cur = -1;
    int iend = i0 + CHK;
    if (iend > NN) iend = NN;
    for (int i = i0; i < iend; ++i) {
        int gid = batch[i];
        if (gid != cur) {
            if (cur >= 0) atomicAdd(&gdesc[cur * GD_COLS + col], acc);
            cur = gid;
            acc = 0.f;
        }
        acc += fmaxf(bf2f(u[i * HC + lane]) * a + s, 0.f);
    }
    if (cur >= 0) atomicAdd(&gdesc[cur * GD_COLS + col], acc);
}

__global__ void final_gemm_kernel(const float* __restrict__ gdesc, const float* __restrict__ lw,
                                  const float* __restrict__ lb, float* __restrict__ out) {
    int g = blockIdx.x;
    int lane = threadIdx.x;
    float a0 = 0.f, a1 = 0.f;
    for (int j = lane; j < GD_COLS; j += 64) {
        float v = gdesc[g * GD_COLS + j];
        a0 += v * lw[j * 2 + 0];
        a1 += v * lw[j * 2 + 1];
    }
    for (int off = 32; off > 0; off >>= 1) {
        a0 += __shfl_down(a0, off);
        a1 += __shfl_down(a1, off);
    }
    if (lane == 0) {
        out[g * 2 + 0] = a0 + lb[0];
        out[g * 2 + 1] = a1 + lb[1];
    }
}

extern "C" void kernel_launch(void* const* d_in, const int* in_sizes, int n_in, void* d_out,
                              int out_size, void* d_ws, size_t ws_size, hipStream_t stream) {
    const float* x = (const float*)d_in[0];
    const int* ei = (const int*)d_in[1];
    const int* batch = (const int*)d_in[2];
    const float* w1_0 = (const float*)d_in[3];
    const float* w1_rest = (const float*)d_in[4];
    const float* b1 = (const float*)d_in[5];
    const float* gm = (const float*)d_in[6];
    const float* bm = (const float*)d_in[7];
    const float* w2 = (const float*)d_in[8];
    const float* b2 = (const float*)d_in[9];
    const float* go = (const float*)d_in[10];
    const float* bo = (const float*)d_in[11];
    const float* lw = (const float*)d_in[12];
    const float* lb = (const float*)d_in[13];
    float* out = (float*)d_out;

    float* stats = (float*)d_ws;                     // NL*256
    float* gdesc = stats + NL * 256;                 // NG*321
    bf16_t* ybuf = (bf16_t*)(gdesc + (size_t)NG * GD_COLS + 64);  // NN*64 bf16
    bf16_t* ubuf = ybuf + (size_t)NN * HC;           // NN*64 bf16
    int* cnt = (int*)(ubuf + (size_t)NN * HC);       // NN
    unsigned short* ssrc = (unsigned short*)(cnt + NN);  // NN*64 ushort

    hipMemsetAsync(cnt, 0, NN * sizeof(int), stream);

    scatter_kernel<<<2048, 256, 0, stream>>>(ei, cnt, ssrc, stats, gdesc);

    layer0_kernel<<<(NN + 63) / 64, 256, 0, stream>>>(x, cnt, ssrc, w1_0, b1, batch, gdesc, ybuf,
                                                      stats);
    gemm64_norm_kernel<<<(NN + 63) / 64, 512, 0, stream>>>(ybuf, w2, b2, stats, gm, bm, ubuf,
                                                           stats + 128);
    for (int l = 1; l < NL; ++l) {
        float* st1 = stats + l * 256;
        float* st2 = st1 + 128;
        float* stPrev = stats + (l - 1) * 256 + 128;
        gather_gemm_kernel<<<(NN + 63) / 64, 512, 0, stream>>>(
            ubuf, stPrev, go + (l - 1) * HC, bo + (l - 1) * HC, cnt, ssrc,
            w1_rest + (size_t)(l - 1) * HC * HC, b1 + l * HC, batch, gdesc, l - 1, ybuf, st1);
        gemm64_norm_kernel<<<(NN + 63) / 64, 512, 0, stream>>>(
            ybuf, w2 + (size_t)l * HC * HC, b2 + l * HC, st1, gm + l * HC, bm + l * HC, ubuf, st2);
    }
    gdesc_last_kernel<<<(NN + 4 * CHK - 1) / (4 * CHK), 256, 0, stream>>>(
        ubuf, stats + 4 * 256 + 128, go + 4 * HC, bo + 4 * HC, batch, gdesc, 4);
    final_gemm_kernel<<<NG, 64, 0, stream>>>(gdesc, lw, lb, out);
}

// Round 7
// 419.714 us; speedup vs baseline: 1.4392x; 1.0633x over previous
//
#include <hip/hip_runtime.h>

#define NN 50000
#define NE 800000
#define NG 512
#define HC 64
#define NL 5
#define GD_COLS 321
#define BN_EPS 1e-5f
#define DEG_CAP 64  // max degree: Poisson(16), P(>64) ~ 1e-18 — fixed-stride edge table

#define SLICE 6250   // NN/8: destination slice per XCD group
#define ECHUNK 3125  // NE/256: edge chunk per block pair-group

typedef unsigned short bf16_t;
typedef unsigned int uiv4 __attribute__((ext_vector_type(4)));
typedef __attribute__((ext_vector_type(8))) short short8v;   // 8 bf16 = 4 VGPRs (MFMA A/B frag)
typedef __attribute__((ext_vector_type(4))) float f32x4;     // MFMA C/D frag
typedef __attribute__((ext_vector_type(4))) unsigned uint4v;

static __device__ __forceinline__ unsigned f2bfbits(float f) {
    unsigned u = __float_as_uint(f);
    return (u + 0x7FFFu + ((u >> 16) & 1u)) >> 16;
}
static __device__ __forceinline__ bf16_t f2bf(float f) { return (bf16_t)f2bfbits(f); }
static __device__ __forceinline__ float bf2f(bf16_t h) {
    return __uint_as_float(((unsigned)h) << 16);
}
static __device__ __forceinline__ float bflo(unsigned w) { return __uint_as_float(w << 16); }
static __device__ __forceinline__ float bfhi(unsigned w) {
    return __uint_as_float(w & 0xffff0000u);
}

// ---- shared MFMA GEMM phase (64 rows): OUT[64x64] = ZW @ WSM + bias, + per-channel stats.
// zw: packed bf16 pairs, row-major [64 rows][33 words]. wsm: W columns as k-pair words.
// Wave wid owns tiles (tr=wid>>1, tc=(wid&1)*2 (+1)).
// A-frag: lane holds A[tr*16+(l&15)][kc*32+8*(l>>4)+0..7]. C/D: col=lane&15, row=(lane>>4)*4+j.
static __device__ __forceinline__ void mfma_gemm_phase(
    const unsigned* zw, const unsigned* wsm, const float* __restrict__ bias,
    bf16_t* __restrict__ out, float* __restrict__ statsOut, float (*redS)[64],
    float (*redQ)[64], int r0, int t, int lane, int wid) {
    int l15 = lane & 15, l4 = lane >> 4;
    int tr = wid >> 1;
    int tc0 = (wid & 1) * 2;
    f32x4 d0 = {0.f, 0.f, 0.f, 0.f}, d1 = {0.f, 0.f, 0.f, 0.f};
    const unsigned* arow = &zw[(tr * 16 + l15) * 33];
    const unsigned* brow0 = &wsm[(tc0 * 16 + l15) * 33];
    const unsigned* brow1 = &wsm[((tc0 + 1) * 16 + l15) * 33];
#pragma unroll
    for (int kc = 0; kc < 2; ++kc) {
        int kb = kc * 16 + l4 * 4;
        uint4v aw = {arow[kb], arow[kb + 1], arow[kb + 2], arow[kb + 3]};
        uint4v bw0 = {brow0[kb], brow0[kb + 1], brow0[kb + 2], brow0[kb + 3]};
        uint4v bw1 = {brow1[kb], brow1[kb + 1], brow1[kb + 2], brow1[kb + 3]};
        short8v af = __builtin_bit_cast(short8v, aw);
        d0 = __builtin_amdgcn_mfma_f32_16x16x32_bf16(af, __builtin_bit_cast(short8v, bw0), d0,
                                                     0, 0, 0);
        d1 = __builtin_amdgcn_mfma_f32_16x16x32_bf16(af, __builtin_bit_cast(short8v, bw1), d1,
                                                     0, 0, 0);
    }
    int c0 = tc0 * 16 + l15, c1 = c0 + 16;
    float bv0 = bias[c0], bv1 = bias[c1];
    float s0 = 0.f, q0 = 0.f, s1 = 0.f, q1 = 0.f;
#pragma unroll
    for (int j = 0; j < 4; ++j) {
        int gr = r0 + tr * 16 + l4 * 4 + j;
        if (gr < NN) {
            float v0 = d0[j] + bv0, v1 = d1[j] + bv1;
            out[(size_t)gr * HC + c0] = f2bf(v0);
            out[(size_t)gr * HC + c1] = f2bf(v1);
            s0 += v0;
            q0 += v0 * v0;
            s1 += v1;
            q1 += v1 * v1;
        }
    }
    s0 += __shfl_xor(s0, 16); s0 += __shfl_xor(s0, 32);
    q0 += __shfl_xor(q0, 16); q0 += __shfl_xor(q0, 32);
    s1 += __shfl_xor(s1, 16); s1 += __shfl_xor(s1, 32);
    q1 += __shfl_xor(q1, 16); q1 += __shfl_xor(q1, 32);
    if (l4 == 0) { redS[wid][c0] = s0; redQ[wid][c0] = q0; }
    else if (l4 == 1) { redS[wid][c1] = s1; redQ[wid][c1] = q1; }
    else if (l4 == 2) { redS[wid][c0 ^ 32] = 0.f; redQ[wid][c0 ^ 32] = 0.f; }
    else { redS[wid][c1 ^ 32] = 0.f; redQ[wid][c1 ^ 32] = 0.f; }
    __syncthreads();
    if (t < 64) {
        float ts = 0.f, t2 = 0.f;
#pragma unroll
        for (int k = 0; k < 8; ++k) {
            ts += redS[k][t];
            t2 += redQ[k][t];
        }
        atomicAdd(&statsOut[t], ts);
        atomicAdd(&statsOut[64 + t], t2);
    }
}

// ---------------- edge table build: XCD-sliced scatter + scratch zeroing ----------------
// grid = 256 chunks x 8 groups; g = blockIdx&7 ~ XCD id. Group g handles destinations in
// [g*SLICE,(g+1)*SLICE) so cnt/ssrc dirty lines stay in ONE XCD's L2.
// NEW: edge-list scans use NONTEMPORAL loads — the 6.4 MB stream must not evict the
// dirty 800 KB ssrc slice from L2 (that churn was the residual 30 MB write-back).
// 4-wide unroll: batch d-loads -> batch atomics -> batch stores (overlap atomic latency).
__global__ __launch_bounds__(256) void scatter_kernel(const int* __restrict__ ei,
                                                      int* __restrict__ cnt,
                                                      unsigned short* __restrict__ ssrc,
                                                      float* __restrict__ stats,
                                                      float* __restrict__ gdesc) {
    int t = threadIdx.x;
    int g = blockIdx.x & 7;
    int c = blockIdx.x >> 3;
    int gt = blockIdx.x * 256 + t;
    int total = gridDim.x * 256;
    for (int i = gt; i < NL * 256; i += total) stats[i] = 0.f;
    for (int i = gt; i < NG * GD_COLS; i += total) gdesc[i] = 0.f;
    int lo = g * SLICE, hi = lo + SLICE;
    int e0 = c * ECHUNK;
    int e1 = e0 + ECHUNK;
    if (e1 > NE) e1 = NE;
    for (int eb = e0; eb < e1; eb += 1024) {
        int ed[4], sd[4], pos[4];
        bool act[4];
#pragma unroll
        for (int k = 0; k < 4; ++k) {
            int e = eb + k * 256 + t;
            act[k] = false;
            ed[k] = 0;
            sd[k] = 0;
            if (e < e1) {
                int d = __builtin_nontemporal_load(&ei[NE + e]);
                if (d >= lo && d < hi) {
                    act[k] = true;
                    ed[k] = d;
                    sd[k] = __builtin_nontemporal_load(&ei[e]);
                }
            }
        }
#pragma unroll
        for (int k = 0; k < 4; ++k)
            if (act[k]) pos[k] = atomicAdd(&cnt[ed[k]], 1);
#pragma unroll
        for (int k = 0; k < 4; ++k)
            if (act[k] && pos[k] < DEG_CAP) ssrc[(ed[k] << 6) + pos[k]] = (unsigned short)sd[k];
    }
}

// ---------------- layer 0: gather0 + rank-1 expand + stats0 + first_desc ----------------
__global__ __launch_bounds__(256) void layer0_kernel(
    const float* __restrict__ x, const int* __restrict__ cnt,
    const unsigned short* __restrict__ ssrc, const float* __restrict__ w,
    const float* __restrict__ bias, const int* __restrict__ batch, float* __restrict__ gdesc,
    bf16_t* __restrict__ y, float* __restrict__ stats) {
    __shared__ float z0p[256];
    __shared__ float z0s[64];
    int t = threadIdx.x, lane = t & 63, wid = t >> 6;
    int r0 = blockIdx.x * 64;
    if (t < 64) {
        int i = r0 + t;
        if (i < NN) atomicAdd(&gdesc[batch[i] * GD_COLS], x[i]);
    }
    {
        int node = t >> 2, sub = t & 3;
        int i = r0 + node;
        float acc = 0.f;
        if (i < NN) {
            int deg = cnt[i];
            if (deg > DEG_CAP) deg = DEG_CAP;
            int pa = i << 6;
            for (int p = sub; p < deg; p += 4) acc += x[ssrc[pa + p]];
            if (sub == 0) acc += x[i];
        }
        z0p[t] = acc;
    }
    __syncthreads();
    if (t < 64) z0s[t] = z0p[4 * t] + z0p[4 * t + 1] + z0p[4 * t + 2] + z0p[4 * t + 3];
    __syncthreads();
    float wv = w[lane], bv = bias[lane];
    float s = 0.f, s2 = 0.f;
    for (int j = 0; j < 16; ++j) {
        int r = r0 + wid * 16 + j;
        if (r < NN) {
            float v = z0s[wid * 16 + j] * wv + bv;
            y[r * HC + lane] = f2bf(v);
            s += v;
            s2 += v * v;
        }
    }
    __shared__ float ls[256], ls2[256];
    ls[t] = s;
    ls2[t] = s2;
    __syncthreads();
    if (wid == 0) {
        float ts = ls[lane] + ls[64 + lane] + ls[128 + lane] + ls[192 + lane];
        float t2 = ls2[lane] + ls2[64 + lane] + ls2[128 + lane] + ls2[192 + lane];
        atomicAdd(&stats[lane], ts);
        atomicAdd(&stats[64 + lane], t2);
    }
}

// ---------------- K1: BN2(prev)+ReLU fused gather + gdesc(prev) + MFMA GEMM1 + stats1 ----
__global__ __launch_bounds__(512, 2) void gather_gemm_kernel(
    const bf16_t* __restrict__ u, const float* __restrict__ statsPrev,
    const float* __restrict__ gPrev, const float* __restrict__ bPrev,
    const int* __restrict__ cnt, const unsigned short* __restrict__ ssrc,
    const float* __restrict__ w, const float* __restrict__ bias, const int* __restrict__ batch,
    float* __restrict__ gdesc, int layerPrev, bf16_t* __restrict__ out,
    float* __restrict__ statsOut) {
    __shared__ unsigned zw[64 * 33];
    __shared__ unsigned wsm[64 * 33];
    __shared__ float a1[64], s1[64];
    __shared__ float redS[8][64], redQ[8][64];
    int t = threadIdx.x, lane = t & 63, wid = t >> 6;
    int r0 = blockIdx.x * 64;
    // --- hoisted Phase-B index + self-row fetch ---
    int li = lane & 7;       // channel slice owner
    int gq = lane >> 3;      // row within wave's 8
    int gbase = lane & 56;   // first lane of this 8-lane group
    int nB = r0 + wid * 8 + gq;
    uiv4 myidx;
    myidx[0] = 0; myidx[1] = 0; myidx[2] = 0; myidx[3] = 0;
    uiv4 selfv;
    selfv[0] = 0; selfv[1] = 0; selfv[2] = 0; selfv[3] = 0;
    int degB = 0;
    if (nB < NN) {
        degB = cnt[nB];
        if (degB > DEG_CAP) degB = DEG_CAP;
        myidx = *(const uiv4*)&ssrc[((size_t)nB << 6) + li * 8];
        selfv = *(const uiv4*)&u[(size_t)nB * HC + li * 8];
    }
    if (t < 64) {
        float mu = statsPrev[t] * (1.0f / NN);
        float var = statsPrev[64 + t] * (1.0f / NN) - mu * mu;
        float a = gPrev[t] * rsqrtf(var + BN_EPS);
        a1[t] = a;
        s1[t] = bPrev[t] - mu * a;
    }
    for (int idx = t; idx < 2048; idx += 512) {
        int kk = idx >> 6, c = idx & 63;
        unsigned lo = f2bfbits(w[(2 * kk) * 64 + c]);
        unsigned hi = f2bfbits(w[(2 * kk + 1) * 64 + c]);
        wsm[c * 33 + kk] = lo | (hi << 16);
    }
    __syncthreads();
    // Phase B: self-term init + edge gather (8-lane groups, shfl-broadcast indices)
    {
        float a8[8], s8[8];
#pragma unroll
        for (int c = 0; c < 8; ++c) {
            a8[c] = a1[li * 8 + c];
            s8[c] = s1[li * 8 + c];
        }
        float acc[8];
        if (nB < NN) {
            acc[0] = fmaxf(bflo(selfv[0]) * a8[0] + s8[0], 0.f);
            acc[1] = fmaxf(bfhi(selfv[0]) * a8[1] + s8[1], 0.f);
            acc[2] = fmaxf(bflo(selfv[1]) * a8[2] + s8[2], 0.f);
            acc[3] = fmaxf(bfhi(selfv[1]) * a8[3] + s8[3], 0.f);
            acc[4] = fmaxf(bflo(selfv[2]) * a8[4] + s8[4], 0.f);
            acc[5] = fmaxf(bfhi(selfv[2]) * a8[5] + s8[5], 0.f);
            acc[6] = fmaxf(bflo(selfv[3]) * a8[6] + s8[6], 0.f);
            acc[7] = fmaxf(bfhi(selfv[3]) * a8[7] + s8[7], 0.f);
        } else {
#pragma unroll
            for (int c = 0; c < 8; ++c) acc[c] = 0.f;
        }
        if (degB > 0) {
            uiv4 rv[8];
            int cntA = degB < 8 ? degB : 8;
            {
                unsigned w0 = __shfl(myidx[0], gbase);
                unsigned w1 = __shfl(myidx[1], gbase);
                unsigned w2 = __shfl(myidx[2], gbase);
                unsigned w3 = __shfl(myidx[3], gbase);
                int id[8] = {(int)(w0 & 0xffff), (int)(w0 >> 16), (int)(w1 & 0xffff),
                             (int)(w1 >> 16),    (int)(w2 & 0xffff), (int)(w2 >> 16),
                             (int)(w3 & 0xffff), (int)(w3 >> 16)};
#pragma unroll
                for (int e = 0; e < 8; ++e)
                    rv[e] = *(const uiv4*)&u[(size_t)id[e] * HC + li * 8];
            }
            for (int b = 1; cntA > 0; ++b) {
                uiv4 nv[8];
                int cntB = 0;
                if (b * 8 < degB) {
                    unsigned w0 = __shfl(myidx[0], gbase + b);
                    unsigned w1 = __shfl(myidx[1], gbase + b);
                    unsigned w2 = __shfl(myidx[2], gbase + b);
                    unsigned w3 = __shfl(myidx[3], gbase + b);
                    int id[8] = {(int)(w0 & 0xffff), (int)(w0 >> 16), (int)(w1 & 0xffff),
                                 (int)(w1 >> 16),    (int)(w2 & 0xffff), (int)(w2 >> 16),
                                 (int)(w3 & 0xffff), (int)(w3 >> 16)};
#pragma unroll
                    for (int e = 0; e < 8; ++e)
                        nv[e] = *(const uiv4*)&u[(size_t)id[e] * HC + li * 8];
                    cntB = degB - b * 8;
                    if (cntB > 8) cntB = 8;
                }
#pragma unroll
                for (int e = 0; e < 8; ++e) {
                    float v0 = fmaxf(bflo(rv[e][0]) * a8[0] + s8[0], 0.f);
                    float v1 = fmaxf(bfhi(rv[e][0]) * a8[1] + s8[1], 0.f);
                    float v2 = fmaxf(bflo(rv[e][1]) * a8[2] + s8[2], 0.f);
                    float v3 = fmaxf(bfhi(rv[e][1]) * a8[3] + s8[3], 0.f);
                    float v4 = fmaxf(bflo(rv[e][2]) * a8[4] + s8[4], 0.f);
                    float v5 = fmaxf(bfhi(rv[e][2]) * a8[5] + s8[5], 0.f);
                    float v6 = fmaxf(bflo(rv[e][3]) * a8[6] + s8[6], 0.f);
                    float v7 = fmaxf(bfhi(rv[e][3]) * a8[7] + s8[7], 0.f);
                    if (e < cntA) {
                        acc[0] += v0;
                        acc[1] += v1;
                        acc[2] += v2;
                        acc[3] += v3;
                        acc[4] += v4;
                        acc[5] += v5;
                        acc[6] += v6;
                        acc[7] += v7;
                    }
                }
#pragma unroll
                for (int e = 0; e < 8; ++e) rv[e] = nv[e];
                cntA = cntB;
            }
        }
        int lr = wid * 8 + gq;
        unsigned* zp = &zw[lr * 33 + li * 4];
        zp[0] = f2bfbits(acc[0]) | (f2bfbits(acc[1]) << 16);
        zp[1] = f2bfbits(acc[2]) | (f2bfbits(acc[3]) << 16);
        zp[2] = f2bfbits(acc[4]) | (f2bfbits(acc[5]) << 16);
        zp[3] = f2bfbits(acc[6]) | (f2bfbits(acc[7]) << 16);
    }
    // Phase A: gdesc segmented sum only (lane = channel)
    {
        float av = a1[lane], sv = s1[lane];
        int col = 1 + layerPrev * HC + lane;
        float gacc = 0.f;
        int cur = -1;
        for (int j = 0; j < 8; ++j) {
            int gr = r0 + wid * 8 + j;
            if (gr < NN) {
                float hv = fmaxf(bf2f(u[(size_t)gr * HC + lane]) * av + sv, 0.f);
                int gid = batch[gr];
                if (gid != cur) {
                    if (cur >= 0) atomicAdd(&gdesc[cur * GD_COLS + col], gacc);
                    cur = gid;
                    gacc = 0.f;
                }
                gacc += hv;
            }
        }
        if (cur >= 0) atomicAdd(&gdesc[cur * GD_COLS + col], gacc);
    }
    __syncthreads();  // zw rows cross waves for MFMA A-frags
    mfma_gemm_phase(zw, wsm, bias, out, statsOut, redS, redQ, r0, t, lane, wid);
}

// ---------------- K2: BN1+ReLU staging + MFMA GEMM2 + stats2 (128 rows/block) ----------
// Wave wid owns rows [wid*16, wid*16+16) x all 4 col-tiles (8 MFMA/wave). Halves the
// per-dispatch fixed cost (BN setup, weight staging, barriers, stats reduce) vs 64-row.
__global__ __launch_bounds__(512) void gemm128_norm_kernel(
    const bf16_t* __restrict__ in, const float* __restrict__ w, const float* __restrict__ bias,
    const float* __restrict__ statsIn, const float* __restrict__ gIn,
    const float* __restrict__ bIn, bf16_t* __restrict__ out, float* __restrict__ statsOut) {
    __shared__ unsigned zw[128 * 33];
    __shared__ unsigned wsm[64 * 33];
    __shared__ float a1[64], s1[64];
    __shared__ float redS[8][64], redQ[8][64];
    int t = threadIdx.x, lane = t & 63, wid = t >> 6;
    int r0 = blockIdx.x * 128;
    if (t < 64) {
        float mu = statsIn[t] * (1.0f / NN);
        float var = statsIn[64 + t] * (1.0f / NN) - mu * mu;
        float a = gIn[t] * rsqrtf(var + BN_EPS);
        a1[t] = a;
        s1[t] = bIn[t] - mu * a;
    }
    for (int idx = t; idx < 2048; idx += 512) {
        int kk = idx >> 6, c = idx & 63;
        unsigned lo = f2bfbits(w[(2 * kk) * 64 + c]);
        unsigned hi = f2bfbits(w[(2 * kk + 1) * 64 + c]);
        wsm[c * 33 + kk] = lo | (hi << 16);
    }
    __syncthreads();
    for (int idx = t; idx < 4096; idx += 512) {
        int r = idx >> 5, kk = idx & 31;
        int gr = r0 + r;
        unsigned zword = 0u;
        if (gr < NN) {
            unsigned word = *(const unsigned*)&in[(size_t)gr * HC + 2 * kk];
            float v0 = fmaxf(bflo(word) * a1[2 * kk] + s1[2 * kk], 0.f);
            float v1 = fmaxf(bfhi(word) * a1[2 * kk + 1] + s1[2 * kk + 1], 0.f);
            zword = f2bfbits(v0) | (f2bfbits(v1) << 16);
        }
        zw[r * 33 + kk] = zword;
    }
    __syncthreads();
    int l15 = lane & 15, l4 = lane >> 4;
    const unsigned* arow = &zw[(wid * 16 + l15) * 33];
    f32x4 d[4];
#pragma unroll
    for (int tc = 0; tc < 4; ++tc) d[tc] = (f32x4){0.f, 0.f, 0.f, 0.f};
#pragma unroll
    for (int kc = 0; kc < 2; ++kc) {
        int kb = kc * 16 + l4 * 4;
        uint4v aw = {arow[kb], arow[kb + 1], arow[kb + 2], arow[kb + 3]};
        short8v af = __builtin_bit_cast(short8v, aw);
#pragma unroll
        for (int tc = 0; tc < 4; ++tc) {
            const unsigned* brow = &wsm[(tc * 16 + l15) * 33];
            uint4v bw = {brow[kb], brow[kb + 1], brow[kb + 2], brow[kb + 3]};
            d[tc] = __builtin_amdgcn_mfma_f32_16x16x32_bf16(af, __builtin_bit_cast(short8v, bw),
                                                            d[tc], 0, 0, 0);
        }
    }
    float ss[4], qq[4];
#pragma unroll
    for (int tc = 0; tc < 4; ++tc) {
        int cc = tc * 16 + l15;
        float bv = bias[cc];
        float s = 0.f, q = 0.f;
#pragma unroll
        for (int j = 0; j < 4; ++j) {
            int gr = r0 + wid * 16 + l4 * 4 + j;
            if (gr < NN) {
                float v = d[tc][j] + bv;
                out[(size_t)gr * HC + cc] = f2bf(v);
                s += v;
                q += v * v;
            }
        }
        s += __shfl_xor(s, 16); s += __shfl_xor(s, 32);
        q += __shfl_xor(q, 16); q += __shfl_xor(q, 32);
        ss[tc] = s;
        qq[tc] = q;
    }
    if (lane < 16) {
#pragma unroll
        for (int tc = 0; tc < 4; ++tc) {
            redS[wid][tc * 16 + lane] = ss[tc];
            redQ[wid][tc * 16 + lane] = qq[tc];
        }
    }
    __syncthreads();
    if (t < 64) {
        float ts = 0.f, t2 = 0.f;
#pragma unroll
        for (int k = 0; k < 8; ++k) {
            ts += redS[k][t];
            t2 += redQ[k][t];
        }
        atomicAdd(&statsOut[t], ts);
        atomicAdd(&statsOut[64 + t], t2);
    }
}

// ---------------- last-layer gdesc (BN2+ReLU, segmented sum, no h write) ----------------
#define CHK 16
__global__ void gdesc_last_kernel(const bf16_t* __restrict__ u, const float* __restrict__ stats,
                                  const float* __restrict__ g, const float* __restrict__ b,
                                  const int* __restrict__ batch, float* __restrict__ gdesc,
                                  int layer) {
    int lane = threadIdx.x & 63;
    int wid = threadIdx.x >> 6;
    int i0 = (blockIdx.x * 4 + wid) * CHK;
    if (i0 >= NN) return;
    float mu = stats[lane] * (1.0f / NN);
    float var = stats[64 + lane] * (1.0f / NN) - mu * mu;
    float a = g[lane] * rsqrtf(var + BN_EPS);
    float s = b[lane] - mu * a;
    int col = 1 + layer * HC + lane;
    float acc = 0.f;
    int cur = -1;
    int iend = i0 + CHK;
    if (iend > NN) iend = NN;
    for (int i = i0; i < iend; ++i) {
        int gid = batch[i];
        if (gid != cur) {
            if (cur >= 0) atomicAdd(&gdesc[cur * GD_COLS + col], acc);
            cur = gid;
            acc = 0.f;
        }
        acc += fmaxf(bf2f(u[i * HC + lane]) * a + s, 0.f);
    }
    if (cur >= 0) atomicAdd(&gdesc[cur * GD_COLS + col], acc);
}

__global__ void final_gemm_kernel(const float* __restrict__ gdesc, const float* __restrict__ lw,
                                  const float* __restrict__ lb, float* __restrict__ out) {
    int g = blockIdx.x;
    int lane = threadIdx.x;
    float a0 = 0.f, a1 = 0.f;
    for (int j = lane; j < GD_COLS; j += 64) {
        float v = gdesc[g * GD_COLS + j];
        a0 += v * lw[j * 2 + 0];
        a1 += v * lw[j * 2 + 1];
    }
    for (int off = 32; off > 0; off >>= 1) {
        a0 += __shfl_down(a0, off);
        a1 += __shfl_down(a1, off);
    }
    if (lane == 0) {
        out[g * 2 + 0] = a0 + lb[0];
        out[g * 2 + 1] = a1 + lb[1];
    }
}

extern "C" void kernel_launch(void* const* d_in, const int* in_sizes, int n_in, void* d_out,
                              int out_size, void* d_ws, size_t ws_size, hipStream_t stream) {
    const float* x = (const float*)d_in[0];
    const int* ei = (const int*)d_in[1];
    const int* batch = (const int*)d_in[2];
    const float* w1_0 = (const float*)d_in[3];
    const float* w1_rest = (const float*)d_in[4];
    const float* b1 = (const float*)d_in[5];
    const float* gm = (const float*)d_in[6];
    const float* bm = (const float*)d_in[7];
    const float* w2 = (const float*)d_in[8];
    const float* b2 = (const float*)d_in[9];
    const float* go = (const float*)d_in[10];
    const float* bo = (const float*)d_in[11];
    const float* lw = (const float*)d_in[12];
    const float* lb = (const float*)d_in[13];
    float* out = (float*)d_out;

    float* stats = (float*)d_ws;                     // NL*256
    float* gdesc = stats + NL * 256;                 // NG*321
    bf16_t* ybuf = (bf16_t*)(gdesc + (size_t)NG * GD_COLS + 64);  // NN*64 bf16
    bf16_t* ubuf = ybuf + (size_t)NN * HC;           // NN*64 bf16
    int* cnt = (int*)(ubuf + (size_t)NN * HC);       // NN
    unsigned short* ssrc = (unsigned short*)(cnt + NN);  // NN*64 ushort

    hipMemsetAsync(cnt, 0, NN * sizeof(int), stream);

    scatter_kernel<<<2048, 256, 0, stream>>>(ei, cnt, ssrc, stats, gdesc);

    layer0_kernel<<<(NN + 63) / 64, 256, 0, stream>>>(x, cnt, ssrc, w1_0, b1, batch, gdesc, ybuf,
                                                      stats);
    gemm128_norm_kernel<<<(NN + 127) / 128, 512, 0, stream>>>(ybuf, w2, b2, stats, gm, bm, ubuf,
                                                              stats + 128);
    for (int l = 1; l < NL; ++l) {
        float* st1 = stats + l * 256;
        float* st2 = st1 + 128;
        float* stPrev = stats + (l - 1) * 256 + 128;
        gather_gemm_kernel<<<(NN + 63) / 64, 512, 0, stream>>>(
            ubuf, stPrev, go + (l - 1) * HC, bo + (l - 1) * HC, cnt, ssrc,
            w1_rest + (size_t)(l - 1) * HC * HC, b1 + l * HC, batch, gdesc, l - 1, ybuf, st1);
        gemm128_norm_kernel<<<(NN + 127) / 128, 512, 0, stream>>>(
            ybuf, w2 + (size_t)l * HC * HC, b2 + l * HC, st1, gm + l * HC, bm + l * HC, ubuf, st2);
    }
    gdesc_last_kernel<<<(NN + 4 * CHK - 1) / (4 * CHK), 256, 0, stream>>>(
        ubuf, stats + 4 * 256 + 128, go + 4 * HC, bo + 4 * HC, batch, gdesc, 4);
    final_gemm_kernel<<<NG, 64, 0, stream>>>(gdesc, lw, lb, out);
}

// Round 8
// 410.641 us; speedup vs baseline: 1.4710x; 1.0221x over previous
//
#include <hip/hip_runtime.h>

#define NN 50000
#define NE 800000
#define NG 512
#define HC 64
#define NL 5
#define GD_COLS 321
#define BN_EPS 1e-5f
#define DEG_CAP 64  // max degree: Poisson(16), P(>64) ~ 1e-18 — fixed-stride edge table

#define SLICE 6250   // NN/8: destination slice per XCD group
#define ECHUNK 3125  // NE/256: edge chunk per block pair-group

typedef unsigned short bf16_t;
typedef unsigned int uiv4 __attribute__((ext_vector_type(4)));
typedef __attribute__((ext_vector_type(8))) short short8v;   // 8 bf16 = 4 VGPRs (MFMA A/B frag)
typedef __attribute__((ext_vector_type(4))) float f32x4;     // MFMA C/D frag
typedef __attribute__((ext_vector_type(4))) unsigned uint4v;

static __device__ __forceinline__ unsigned f2bfbits(float f) {
    unsigned u = __float_as_uint(f);
    return (u + 0x7FFFu + ((u >> 16) & 1u)) >> 16;
}
static __device__ __forceinline__ bf16_t f2bf(float f) { return (bf16_t)f2bfbits(f); }
static __device__ __forceinline__ float bf2f(bf16_t h) {
    return __uint_as_float(((unsigned)h) << 16);
}
static __device__ __forceinline__ float bflo(unsigned w) { return __uint_as_float(w << 16); }
static __device__ __forceinline__ float bfhi(unsigned w) {
    return __uint_as_float(w & 0xffff0000u);
}

// ---- shared MFMA GEMM phase (64 rows): OUT[64x64] = ZW @ WSM + bias, + per-channel stats.
// zw: packed bf16 pairs, row-major [64 rows][33 words]. wsm: W columns as k-pair words.
// Wave wid owns tiles (tr=wid>>1, tc=(wid&1)*2 (+1)).
// A-frag: lane holds A[tr*16+(l&15)][kc*32+8*(l>>4)+0..7]. C/D: col=lane&15, row=(lane>>4)*4+j.
static __device__ __forceinline__ void mfma_gemm_phase(
    const unsigned* zw, const unsigned* wsm, const float* __restrict__ bias,
    bf16_t* __restrict__ out, float* __restrict__ statsOut, float (*redS)[64],
    float (*redQ)[64], int r0, int t, int lane, int wid) {
    int l15 = lane & 15, l4 = lane >> 4;
    int tr = wid >> 1;
    int tc0 = (wid & 1) * 2;
    f32x4 d0 = {0.f, 0.f, 0.f, 0.f}, d1 = {0.f, 0.f, 0.f, 0.f};
    const unsigned* arow = &zw[(tr * 16 + l15) * 33];
    const unsigned* brow0 = &wsm[(tc0 * 16 + l15) * 33];
    const unsigned* brow1 = &wsm[((tc0 + 1) * 16 + l15) * 33];
#pragma unroll
    for (int kc = 0; kc < 2; ++kc) {
        int kb = kc * 16 + l4 * 4;
        uint4v aw = {arow[kb], arow[kb + 1], arow[kb + 2], arow[kb + 3]};
        uint4v bw0 = {brow0[kb], brow0[kb + 1], brow0[kb + 2], brow0[kb + 3]};
        uint4v bw1 = {brow1[kb], brow1[kb + 1], brow1[kb + 2], brow1[kb + 3]};
        short8v af = __builtin_bit_cast(short8v, aw);
        d0 = __builtin_amdgcn_mfma_f32_16x16x32_bf16(af, __builtin_bit_cast(short8v, bw0), d0,
                                                     0, 0, 0);
        d1 = __builtin_amdgcn_mfma_f32_16x16x32_bf16(af, __builtin_bit_cast(short8v, bw1), d1,
                                                     0, 0, 0);
    }
    int c0 = tc0 * 16 + l15, c1 = c0 + 16;
    float bv0 = bias[c0], bv1 = bias[c1];
    float s0 = 0.f, q0 = 0.f, s1 = 0.f, q1 = 0.f;
#pragma unroll
    for (int j = 0; j < 4; ++j) {
        int gr = r0 + tr * 16 + l4 * 4 + j;
        if (gr < NN) {
            float v0 = d0[j] + bv0, v1 = d1[j] + bv1;
            out[(size_t)gr * HC + c0] = f2bf(v0);
            out[(size_t)gr * HC + c1] = f2bf(v1);
            s0 += v0;
            q0 += v0 * v0;
            s1 += v1;
            q1 += v1 * v1;
        }
    }
    s0 += __shfl_xor(s0, 16); s0 += __shfl_xor(s0, 32);
    q0 += __shfl_xor(q0, 16); q0 += __shfl_xor(q0, 32);
    s1 += __shfl_xor(s1, 16); s1 += __shfl_xor(s1, 32);
    q1 += __shfl_xor(q1, 16); q1 += __shfl_xor(q1, 32);
    if (l4 == 0) { redS[wid][c0] = s0; redQ[wid][c0] = q0; }
    else if (l4 == 1) { redS[wid][c1] = s1; redQ[wid][c1] = q1; }
    else if (l4 == 2) { redS[wid][c0 ^ 32] = 0.f; redQ[wid][c0 ^ 32] = 0.f; }
    else { redS[wid][c1 ^ 32] = 0.f; redQ[wid][c1 ^ 32] = 0.f; }
    __syncthreads();
    if (t < 64) {
        float ts = 0.f, t2 = 0.f;
#pragma unroll
        for (int k = 0; k < 8; ++k) {
            ts += redS[k][t];
            t2 += redQ[k][t];
        }
        atomicAdd(&statsOut[t], ts);
        atomicAdd(&statsOut[64 + t], t2);
    }
}

// ---------------- edge table build: XCD-sliced scatter + scratch zeroing ----------------
// grid = 256 chunks x 8 groups; g = blockIdx&7 ~ XCD id. Group g handles destinations in
// [g*SLICE,(g+1)*SLICE) so cnt/ssrc dirty lines stay in ONE XCD's L2 (round-6 form —
// the NT-load + unroll variant of round 7 was a measured regression and is reverted).
__global__ __launch_bounds__(256) void scatter_kernel(const int* __restrict__ ei,
                                                      int* __restrict__ cnt,
                                                      unsigned short* __restrict__ ssrc,
                                                      float* __restrict__ stats,
                                                      float* __restrict__ gdesc) {
    int t = threadIdx.x;
    int g = blockIdx.x & 7;
    int c = blockIdx.x >> 3;
    int gt = blockIdx.x * 256 + t;
    int total = gridDim.x * 256;
    for (int i = gt; i < NL * 256; i += total) stats[i] = 0.f;
    for (int i = gt; i < NG * GD_COLS; i += total) gdesc[i] = 0.f;
    int lo = g * SLICE, hi = lo + SLICE;
    int e0 = c * ECHUNK;
    int e1 = e0 + ECHUNK;
    if (e1 > NE) e1 = NE;
    for (int e = e0 + t; e < e1; e += 256) {
        int d = ei[NE + e];
        if (d >= lo && d < hi) {
            int s = ei[e];
            int pos = atomicAdd(&cnt[d], 1);
            if (pos < DEG_CAP) ssrc[(d << 6) + pos] = (unsigned short)s;
        }
    }
}

// ---------------- layer 0: gather0 + rank-1 expand + stats0 + first_desc ----------------
__global__ __launch_bounds__(256) void layer0_kernel(
    const float* __restrict__ x, const int* __restrict__ cnt,
    const unsigned short* __restrict__ ssrc, const float* __restrict__ w,
    const float* __restrict__ bias, const int* __restrict__ batch, float* __restrict__ gdesc,
    bf16_t* __restrict__ y, float* __restrict__ stats) {
    __shared__ float z0p[256];
    __shared__ float z0s[64];
    int t = threadIdx.x, lane = t & 63, wid = t >> 6;
    int r0 = blockIdx.x * 64;
    if (t < 64) {
        int i = r0 + t;
        if (i < NN) atomicAdd(&gdesc[batch[i] * GD_COLS], x[i]);
    }
    {
        int node = t >> 2, sub = t & 3;
        int i = r0 + node;
        float acc = 0.f;
        if (i < NN) {
            int deg = cnt[i];
            if (deg > DEG_CAP) deg = DEG_CAP;
            int pa = i << 6;
            for (int p = sub; p < deg; p += 4) acc += x[ssrc[pa + p]];
            if (sub == 0) acc += x[i];
        }
        z0p[t] = acc;
    }
    __syncthreads();
    if (t < 64) z0s[t] = z0p[4 * t] + z0p[4 * t + 1] + z0p[4 * t + 2] + z0p[4 * t + 3];
    __syncthreads();
    float wv = w[lane], bv = bias[lane];
    float s = 0.f, s2 = 0.f;
    for (int j = 0; j < 16; ++j) {
        int r = r0 + wid * 16 + j;
        if (r < NN) {
            float v = z0s[wid * 16 + j] * wv + bv;
            y[r * HC + lane] = f2bf(v);
            s += v;
            s2 += v * v;
        }
    }
    __shared__ float ls[256], ls2[256];
    ls[t] = s;
    ls2[t] = s2;
    __syncthreads();
    if (wid == 0) {
        float ts = ls[lane] + ls[64 + lane] + ls[128 + lane] + ls[192 + lane];
        float t2 = ls2[lane] + ls2[64 + lane] + ls2[128 + lane] + ls2[192 + lane];
        atomicAdd(&stats[lane], ts);
        atomicAdd(&stats[64 + lane], t2);
    }
}

// ---------------- K1: BN2(prev)+ReLU fused gather + gdesc(prev) + MFMA GEMM1 + stats1 ----
// NEW: batch-0 edge-row loads (rv0) hoisted to kernel entry — they depend only on myidx,
// so the BN setup + 2048-load weight staging + barrier hide their ~600-cycle latency
// instead of exposing it at the head of Phase B.
__global__ __launch_bounds__(512, 2) void gather_gemm_kernel(
    const bf16_t* __restrict__ u, const float* __restrict__ statsPrev,
    const float* __restrict__ gPrev, const float* __restrict__ bPrev,
    const int* __restrict__ cnt, const unsigned short* __restrict__ ssrc,
    const float* __restrict__ w, const float* __restrict__ bias, const int* __restrict__ batch,
    float* __restrict__ gdesc, int layerPrev, bf16_t* __restrict__ out,
    float* __restrict__ statsOut) {
    __shared__ unsigned zw[64 * 33];
    __shared__ unsigned wsm[64 * 33];
    __shared__ float a1[64], s1[64];
    __shared__ float redS[8][64], redQ[8][64];
    int t = threadIdx.x, lane = t & 63, wid = t >> 6;
    int r0 = blockIdx.x * 64;
    // --- hoisted Phase-B index + self-row fetch ---
    int li = lane & 7;       // channel slice owner
    int gq = lane >> 3;      // row within wave's 8
    int gbase = lane & 56;   // first lane of this 8-lane group
    int nB = r0 + wid * 8 + gq;
    uiv4 myidx;
    myidx[0] = 0; myidx[1] = 0; myidx[2] = 0; myidx[3] = 0;
    uiv4 selfv;
    selfv[0] = 0; selfv[1] = 0; selfv[2] = 0; selfv[3] = 0;
    int degB = 0;
    if (nB < NN) {
        degB = cnt[nB];
        if (degB > DEG_CAP) degB = DEG_CAP;
        myidx = *(const uiv4*)&ssrc[((size_t)nB << 6) + li * 8];
        selfv = *(const uiv4*)&u[(size_t)nB * HC + li * 8];
    }
    // --- hoisted batch-0 gather loads (masked lanes read u[0..] harmlessly) ---
    uiv4 rv0[8];
    {
        unsigned w0 = __shfl(myidx[0], gbase);
        unsigned w1 = __shfl(myidx[1], gbase);
        unsigned w2 = __shfl(myidx[2], gbase);
        unsigned w3 = __shfl(myidx[3], gbase);
        int id[8] = {(int)(w0 & 0xffff), (int)(w0 >> 16), (int)(w1 & 0xffff),
                     (int)(w1 >> 16),    (int)(w2 & 0xffff), (int)(w2 >> 16),
                     (int)(w3 & 0xffff), (int)(w3 >> 16)};
#pragma unroll
        for (int e = 0; e < 8; ++e)
            rv0[e] = *(const uiv4*)&u[(size_t)id[e] * HC + li * 8];
    }
    if (t < 64) {
        float mu = statsPrev[t] * (1.0f / NN);
        float var = statsPrev[64 + t] * (1.0f / NN) - mu * mu;
        float a = gPrev[t] * rsqrtf(var + BN_EPS);
        a1[t] = a;
        s1[t] = bPrev[t] - mu * a;
    }
    for (int idx = t; idx < 2048; idx += 512) {
        int kk = idx >> 6, c = idx & 63;
        unsigned lo = f2bfbits(w[(2 * kk) * 64 + c]);
        unsigned hi = f2bfbits(w[(2 * kk + 1) * 64 + c]);
        wsm[c * 33 + kk] = lo | (hi << 16);
    }
    __syncthreads();
    // Phase B: self-term init + edge gather (8-lane groups, shfl-broadcast indices)
    {
        float a8[8], s8[8];
#pragma unroll
        for (int c = 0; c < 8; ++c) {
            a8[c] = a1[li * 8 + c];
            s8[c] = s1[li * 8 + c];
        }
        float acc[8];
        if (nB < NN) {
            acc[0] = fmaxf(bflo(selfv[0]) * a8[0] + s8[0], 0.f);
            acc[1] = fmaxf(bfhi(selfv[0]) * a8[1] + s8[1], 0.f);
            acc[2] = fmaxf(bflo(selfv[1]) * a8[2] + s8[2], 0.f);
            acc[3] = fmaxf(bfhi(selfv[1]) * a8[3] + s8[3], 0.f);
            acc[4] = fmaxf(bflo(selfv[2]) * a8[4] + s8[4], 0.f);
            acc[5] = fmaxf(bfhi(selfv[2]) * a8[5] + s8[5], 0.f);
            acc[6] = fmaxf(bflo(selfv[3]) * a8[6] + s8[6], 0.f);
            acc[7] = fmaxf(bfhi(selfv[3]) * a8[7] + s8[7], 0.f);
        } else {
#pragma unroll
            for (int c = 0; c < 8; ++c) acc[c] = 0.f;
        }
        if (degB > 0) {
            uiv4 rv[8];
#pragma unroll
            for (int e = 0; e < 8; ++e) rv[e] = rv0[e];
            int cntA = degB < 8 ? degB : 8;
            for (int b = 1; cntA > 0; ++b) {
                uiv4 nv[8];
                int cntB = 0;
                if (b * 8 < degB) {
                    unsigned w0 = __shfl(myidx[0], gbase + b);
                    unsigned w1 = __shfl(myidx[1], gbase + b);
                    unsigned w2 = __shfl(myidx[2], gbase + b);
                    unsigned w3 = __shfl(myidx[3], gbase + b);
                    int id[8] = {(int)(w0 & 0xffff), (int)(w0 >> 16), (int)(w1 & 0xffff),
                                 (int)(w1 >> 16),    (int)(w2 & 0xffff), (int)(w2 >> 16),
                                 (int)(w3 & 0xffff), (int)(w3 >> 16)};
#pragma unroll
                    for (int e = 0; e < 8; ++e)
                        nv[e] = *(const uiv4*)&u[(size_t)id[e] * HC + li * 8];
                    cntB = degB - b * 8;
                    if (cntB > 8) cntB = 8;
                }
#pragma unroll
                for (int e = 0; e < 8; ++e) {
                    float v0 = fmaxf(bflo(rv[e][0]) * a8[0] + s8[0], 0.f);
                    float v1 = fmaxf(bfhi(rv[e][0]) * a8[1] + s8[1], 0.f);
                    float v2 = fmaxf(bflo(rv[e][1]) * a8[2] + s8[2], 0.f);
                    float v3 = fmaxf(bfhi(rv[e][1]) * a8[3] + s8[3], 0.f);
                    float v4 = fmaxf(bflo(rv[e][2]) * a8[4] + s8[4], 0.f);
                    float v5 = fmaxf(bfhi(rv[e][2]) * a8[5] + s8[5], 0.f);
                    float v6 = fmaxf(bflo(rv[e][3]) * a8[6] + s8[6], 0.f);
                    float v7 = fmaxf(bfhi(rv[e][3]) * a8[7] + s8[7], 0.f);
                    if (e < cntA) {
                        acc[0] += v0;
                        acc[1] += v1;
                        acc[2] += v2;
                        acc[3] += v3;
                        acc[4] += v4;
                        acc[5] += v5;
                        acc[6] += v6;
                        acc[7] += v7;
                    }
                }
#pragma unroll
                for (int e = 0; e < 8; ++e) rv[e] = nv[e];
                cntA = cntB;
            }
        }
        int lr = wid * 8 + gq;
        unsigned* zp = &zw[lr * 33 + li * 4];
        zp[0] = f2bfbits(acc[0]) | (f2bfbits(acc[1]) << 16);
        zp[1] = f2bfbits(acc[2]) | (f2bfbits(acc[3]) << 16);
        zp[2] = f2bfbits(acc[4]) | (f2bfbits(acc[5]) << 16);
        zp[3] = f2bfbits(acc[6]) | (f2bfbits(acc[7]) << 16);
    }
    // Phase A: gdesc segmented sum only (lane = channel)
    {
        float av = a1[lane], sv = s1[lane];
        int col = 1 + layerPrev * HC + lane;
        float gacc = 0.f;
        int cur = -1;
        for (int j = 0; j < 8; ++j) {
            int gr = r0 + wid * 8 + j;
            if (gr < NN) {
                float hv = fmaxf(bf2f(u[(size_t)gr * HC + lane]) * av + sv, 0.f);
                int gid = batch[gr];
                if (gid != cur) {
                    if (cur >= 0) atomicAdd(&gdesc[cur * GD_COLS + col], gacc);
                    cur = gid;
                    gacc = 0.f;
                }
                gacc += hv;
            }
        }
        if (cur >= 0) atomicAdd(&gdesc[cur * GD_COLS + col], gacc);
    }
    __syncthreads();  // zw rows cross waves for MFMA A-frags
    mfma_gemm_phase(zw, wsm, bias, out, statsOut, redS, redQ, r0, t, lane, wid);
}

// ---------------- K2: BN1+ReLU staging + MFMA GEMM2 + stats2 (128 rows/block) ----------
__global__ __launch_bounds__(512) void gemm128_norm_kernel(
    const bf16_t* __restrict__ in, const float* __restrict__ w, const float* __restrict__ bias,
    const float* __restrict__ statsIn, const float* __restrict__ gIn,
    const float* __restrict__ bIn, bf16_t* __restrict__ out, float* __restrict__ statsOut) {
    __shared__ unsigned zw[128 * 33];
    __shared__ unsigned wsm[64 * 33];
    __shared__ float a1[64], s1[64];
    __shared__ float redS[8][64], redQ[8][64];
    int t = threadIdx.x, lane = t & 63, wid = t >> 6;
    int r0 = blockIdx.x * 128;
    if (t < 64) {
        float mu = statsIn[t] * (1.0f / NN);
        float var = statsIn[64 + t] * (1.0f / NN) - mu * mu;
        float a = gIn[t] * rsqrtf(var + BN_EPS);
        a1[t] = a;
        s1[t] = bIn[t] - mu * a;
    }
    for (int idx = t; idx < 2048; idx += 512) {
        int kk = idx >> 6, c = idx & 63;
        unsigned lo = f2bfbits(w[(2 * kk) * 64 + c]);
        unsigned hi = f2bfbits(w[(2 * kk + 1) * 64 + c]);
        wsm[c * 33 + kk] = lo | (hi << 16);
    }
    __syncthreads();
    for (int idx = t; idx < 4096; idx += 512) {
        int r = idx >> 5, kk = idx & 31;
        int gr = r0 + r;
        unsigned zword = 0u;
        if (gr < NN) {
            unsigned word = *(const unsigned*)&in[(size_t)gr * HC + 2 * kk];
            float v0 = fmaxf(bflo(word) * a1[2 * kk] + s1[2 * kk], 0.f);
            float v1 = fmaxf(bfhi(word) * a1[2 * kk + 1] + s1[2 * kk + 1], 0.f);
            zword = f2bfbits(v0) | (f2bfbits(v1) << 16);
        }
        zw[r * 33 + kk] = zword;
    }
    __syncthreads();
    int l15 = lane & 15, l4 = lane >> 4;
    const unsigned* arow = &zw[(wid * 16 + l15) * 33];
    f32x4 d[4];
#pragma unroll
    for (int tc = 0; tc < 4; ++tc) d[tc] = (f32x4){0.f, 0.f, 0.f, 0.f};
#pragma unroll
    for (int kc = 0; kc < 2; ++kc) {
        int kb = kc * 16 + l4 * 4;
        uint4v aw = {arow[kb], arow[kb + 1], arow[kb + 2], arow[kb + 3]};
        short8v af = __builtin_bit_cast(short8v, aw);
#pragma unroll
        for (int tc = 0; tc < 4; ++tc) {
            const unsigned* brow = &wsm[(tc * 16 + l15) * 33];
            uint4v bw = {brow[kb], brow[kb + 1], brow[kb + 2], brow[kb + 3]};
            d[tc] = __builtin_amdgcn_mfma_f32_16x16x32_bf16(af, __builtin_bit_cast(short8v, bw),
                                                            d[tc], 0, 0, 0);
        }
    }
    float ss[4], qq[4];
#pragma unroll
    for (int tc = 0; tc < 4; ++tc) {
        int cc = tc * 16 + l15;
        float bv = bias[cc];
        float s = 0.f, q = 0.f;
#pragma unroll
        for (int j = 0; j < 4; ++j) {
            int gr = r0 + wid * 16 + l4 * 4 + j;
            if (gr < NN) {
                float v = d[tc][j] + bv;
                out[(size_t)gr * HC + cc] = f2bf(v);
                s += v;
                q += v * v;
            }
        }
        s += __shfl_xor(s, 16); s += __shfl_xor(s, 32);
        q += __shfl_xor(q, 16); q += __shfl_xor(q, 32);
        ss[tc] = s;
        qq[tc] = q;
    }
    if (lane < 16) {
#pragma unroll
        for (int tc = 0; tc < 4; ++tc) {
            redS[wid][tc * 16 + lane] = ss[tc];
            redQ[wid][tc * 16 + lane] = qq[tc];
        }
    }
    __syncthreads();
    if (t < 64) {
        float ts = 0.f, t2 = 0.f;
#pragma unroll
        for (int k = 0; k < 8; ++k) {
            ts += redS[k][t];
            t2 += redQ[k][t];
        }
        atomicAdd(&statsOut[t], ts);
        atomicAdd(&statsOut[64 + t], t2);
    }
}

// ---------------- last-layer gdesc (BN2+ReLU, segmented sum, no h write) ----------------
#define CHK 16
__global__ void gdesc_last_kernel(const bf16_t* __restrict__ u, const float* __restrict__ stats,
                                  const float* __restrict__ g, const float* __restrict__ b,
                                  const int* __restrict__ batch, float* __restrict__ gdesc,
                                  int layer) {
    int lane = threadIdx.x & 63;
    int wid = threadIdx.x >> 6;
    int i0 = (blockIdx.x * 4 + wid) * CHK;
    if (i0 >= NN) return;
    float mu = stats[lane] * (1.0f / NN);
    float var = stats[64 + lane] * (1.0f / NN) - mu * mu;
    float a = g[lane] * rsqrtf(var + BN_EPS);
    float s = b[lane] - mu * a;
    int col = 1 + layer * HC + lane;
    float acc = 0.f;
    int cur = -1;
    int iend = i0 + CHK;
    if (iend > NN) iend = NN;
    for (int i = i0; i < iend; ++i) {
        int gid = batch[i];
        if (gid != cur) {
            if (cur >= 0) atomicAdd(&gdesc[cur * GD_COLS + col], acc);
            cur = gid;
            acc = 0.f;
        }
        acc += fmaxf(bf2f(u[i * HC + lane]) * a + s, 0.f);
    }
    if (cur >= 0) atomicAdd(&gdesc[cur * GD_COLS + col], acc);
}

__global__ void final_gemm_kernel(const float* __restrict__ gdesc, const float* __restrict__ lw,
                                  const float* __restrict__ lb, float* __restrict__ out) {
    int g = blockIdx.x;
    int lane = threadIdx.x;
    float a0 = 0.f, a1 = 0.f;
    for (int j = lane; j < GD_COLS; j += 64) {
        float v = gdesc[g * GD_COLS + j];
        a0 += v * lw[j * 2 + 0];
        a1 += v * lw[j * 2 + 1];
    }
    for (int off = 32; off > 0; off >>= 1) {
        a0 += __shfl_down(a0, off);
        a1 += __shfl_down(a1, off);
    }
    if (lane == 0) {
        out[g * 2 + 0] = a0 + lb[0];
        out[g * 2 + 1] = a1 + lb[1];
    }
}

extern "C" void kernel_launch(void* const* d_in, const int* in_sizes, int n_in, void* d_out,
                              int out_size, void* d_ws, size_t ws_size, hipStream_t stream) {
    const float* x = (const float*)d_in[0];
    const int* ei = (const int*)d_in[1];
    const int* batch = (const int*)d_in[2];
    const float* w1_0 = (const float*)d_in[3];
    const float* w1_rest = (const float*)d_in[4];
    const float* b1 = (const float*)d_in[5];
    const float* gm = (const float*)d_in[6];
    const float* bm = (const float*)d_in[7];
    const float* w2 = (const float*)d_in[8];
    const float* b2 = (const float*)d_in[9];
    const float* go = (const float*)d_in[10];
    const float* bo = (const float*)d_in[11];
    const float* lw = (const float*)d_in[12];
    const float* lb = (const float*)d_in[13];
    float* out = (float*)d_out;

    float* stats = (float*)d_ws;                     // NL*256
    float* gdesc = stats + NL * 256;                 // NG*321
    bf16_t* ybuf = (bf16_t*)(gdesc + (size_t)NG * GD_COLS + 64);  // NN*64 bf16
    bf16_t* ubuf = ybuf + (size_t)NN * HC;           // NN*64 bf16
    int* cnt = (int*)(ubuf + (size_t)NN * HC);       // NN
    unsigned short* ssrc = (unsigned short*)(cnt + NN);  // NN*64 ushort

    hipMemsetAsync(cnt, 0, NN * sizeof(int), stream);

    scatter_kernel<<<2048, 256, 0, stream>>>(ei, cnt, ssrc, stats, gdesc);

    layer0_kernel<<<(NN + 63) / 64, 256, 0, stream>>>(x, cnt, ssrc, w1_0, b1, batch, gdesc, ybuf,
                                                      stats);
    gemm128_norm_kernel<<<(NN + 127) / 128, 512, 0, stream>>>(ybuf, w2, b2, stats, gm, bm, ubuf,
                                                              stats + 128);
    for (int l = 1; l < NL; ++l) {
        float* st1 = stats + l * 256;
        float* st2 = st1 + 128;
        float* stPrev = stats + (l - 1) * 256 + 128;
        gather_gemm_kernel<<<(NN + 63) / 64, 512, 0, stream>>>(
            ubuf, stPrev, go + (l - 1) * HC, bo + (l - 1) * HC, cnt, ssrc,
            w1_rest + (size_t)(l - 1) * HC * HC, b1 + l * HC, batch, gdesc, l - 1, ybuf, st1);
        gemm128_norm_kernel<<<(NN + 127) / 128, 512, 0, stream>>>(
            ybuf, w2 + (size_t)l * HC * HC, b2 + l * HC, st1, gm + l * HC, bm + l * HC, ubuf, st2);
    }
    gdesc_last_kernel<<<(NN + 4 * CHK - 1) / (4 * CHK), 256, 0, stream>>>(
        ubuf, stats + 4 * 256 + 128, go + 4 * HC, bo + 4 * HC, batch, gdesc, 4);
    final_gemm_kernel<<<NG, 64, 0, stream>>>(gdesc, lw, lb, out);
}